// Round 7
// baseline (331.533 us; speedup 1.0000x reference)
//
#include <hip/hip_runtime.h>
#include <math.h>

#define H 128
#define KE 256      // eW1 MFMA K (k=256,257 via fp32 rank-1 update folded into staging)
#define KN 256      // node GEMM1 K (2H)
#define XSTR 136    // LDS X row stride (bf16 elems)

typedef __attribute__((ext_vector_type(8))) short bf16x8;
typedef __attribute__((ext_vector_type(4))) float f32x4;

__device__ __forceinline__ float fast_rcp(float x) {
#if defined(__has_builtin) && __has_builtin(__builtin_amdgcn_rcpf)
    return __builtin_amdgcn_rcpf(x);
#else
    return 1.0f / x;
#endif
}
__device__ __forceinline__ float fast_rsq(float x) {
#if defined(__has_builtin) && __has_builtin(__builtin_amdgcn_rsqf)
    return __builtin_amdgcn_rsqf(x);
#else
    return rsqrtf(x);
#endif
}
__device__ __forceinline__ float fast_sqrt(float x) {
#if defined(__has_builtin) && __has_builtin(__builtin_amdgcn_sqrtf)
    return __builtin_amdgcn_sqrtf(x);
#else
    return sqrtf(x);
#endif
}

// silu via v_rcp_f32 (1 ulp) instead of IEEE divide expansion (~10-14 VALU ops)
__device__ __forceinline__ float silu_f(float x) {
    return x * fast_rcp(1.0f + __expf(-x));
}

__device__ __forceinline__ unsigned short f2bf(float f) {
    unsigned int u = __float_as_uint(f);
    unsigned int r = u + 0x7FFFu + ((u >> 16) & 1u);
    return (unsigned short)(r >> 16);
}

__device__ __forceinline__ unsigned int pkbf(float a, float b) {
#if defined(__has_builtin)
#if __has_builtin(__builtin_amdgcn_cvt_pk_bf16_f32)
    typedef __attribute__((ext_vector_type(2))) __bf16 bf16x2_t;
    bf16x2_t v = __builtin_amdgcn_cvt_pk_bf16_f32(a, b);
    return *(unsigned int*)&v;
#else
    return (unsigned int)f2bf(a) | ((unsigned int)f2bf(b) << 16);
#endif
#else
    return (unsigned int)f2bf(a) | ((unsigned int)f2bf(b) << 16);
#endif
}

__device__ __forceinline__ float bflo(unsigned int w) { return __uint_as_float(w << 16); }
__device__ __forceinline__ float bfhi(unsigned int w) { return __uint_as_float(w & 0xFFFF0000u); }
__device__ __forceinline__ float bfu(unsigned short u) {
    return __uint_as_float((unsigned int)u << 16);
}

// hardware packed-bf16 atomic add (gfx90a+/gfx950), fire-and-forget
__device__ __forceinline__ void atomic_pk_add_bf16(unsigned short* addr, unsigned int pkv) {
    asm volatile("global_atomic_pk_add_bf16 %0, %1, off"
                 :: "v"(addr), "v"(pkv) : "memory");
}

// ---- 16-lane sum reduction via DPP row rotations ----
template<int CTRL>
__device__ __forceinline__ float dpp_add(float x) {
    int t = __builtin_amdgcn_update_dpp(0, __float_as_int(x), CTRL, 0xF, 0xF, true);
    return x + __int_as_float(t);
}
__device__ __forceinline__ float red16(float x) {
    x = dpp_add<0x128>(x);
    x = dpp_add<0x124>(x);
    x = dpp_add<0x122>(x);
    x = dpp_add<0x121>(x);
    return x;
}

// ---- one weight fragment: W[K][128] fp32 -> fragment-linear Wf[f][8] bf16 ----
__device__ __forceinline__ void wfrag(const float* __restrict__ W,
                                      unsigned short* __restrict__ Wf, int f) {
    int kb = f >> 9, rem = f & 511;
    int nt = rem >> 6, lane = rem & 63;
    int quad = lane >> 4, l15 = lane & 15;
    int n = nt * 16 + l15, k0 = kb * 32 + quad * 8;
    union { bf16x8 v; unsigned short u[8]; } pk;
    #pragma unroll
    for (int j = 0; j < 8; ++j) pk.u[j] = f2bf(W[(size_t)(k0 + j) * H + n]);
    *(bf16x8*)&Wf[(size_t)f * 8] = pk.v;
}

// ---- fused prep: hb convert | aggb zero | coord copy | 5 weight transposes ----
__global__ __launch_bounds__(256) void prep_all(
    const float* __restrict__ h, unsigned short* __restrict__ hb, int n4_h,
    float* __restrict__ aggz, int n4_agg,
    const float* __restrict__ coord, float* __restrict__ coord_out, int n_coord,
    const float* __restrict__ eW1, const float* __restrict__ eW2,
    const float* __restrict__ cW1, const float* __restrict__ nW1,
    const float* __restrict__ nW2,
    unsigned short* __restrict__ eW1f, unsigned short* __restrict__ eW2f,
    unsigned short* __restrict__ cW1f, unsigned short* __restrict__ nW1f,
    unsigned short* __restrict__ nW2f,
    int b0, int b1, int b2)
{
    int b = blockIdx.x;
    int t = threadIdx.x;
    if (b < b0) {
        int i = b * 256 + t;
        if (i < n4_h) {
            float4 f = ((const float4*)h)[i];
            ((uint2*)hb)[i] = make_uint2(pkbf(f.x, f.y), pkbf(f.z, f.w));
        }
    } else if (b < b1) {
        int i = (b - b0) * 256 + t;
        if (i < n4_agg) ((float4*)aggz)[i] = (float4){0.f, 0.f, 0.f, 0.f};
    } else if (b < b2) {
        int i = (b - b1) * 256 + t;
        if (i < n_coord) coord_out[i] = coord[i];
    } else {
        int idx = (b - b2) * 256 + t;
        if      (idx <  4096) wfrag(eW1, eW1f, idx);
        else if (idx <  8192) wfrag(nW1, nW1f, idx - 4096);
        else if (idx < 10240) wfrag(eW2, eW2f, idx - 8192);
        else if (idx < 12288) wfrag(cW1, cW1f, idx - 10240);
        else if (idx < 14336) wfrag(nW2, nW2f, idx - 12288);
    }
}

// ---- proj kernel: Pb[n][0:128] = h[n]@eW1[0:128,:], Pb[n][128:256] = h[n]@eW1[128:256,:]
__global__ __launch_bounds__(256, 4) void proj_kernel(
    const unsigned short* __restrict__ hb,
    const unsigned short* __restrict__ eW1f,
    unsigned short* __restrict__ Pb, int N)
{
    __shared__ unsigned short Ys[4][16 * 256];   // 8 KB per wave

    const int wv = threadIdx.x >> 6;
    const int lane = threadIdx.x & 63;
    const int l15 = lane & 15, quad = lane >> 4;
    const int gn0 = (blockIdx.x * 4 + wv) * 16;
    unsigned short* Y = &Ys[wv][0];

    if (gn0 >= N) return;
    int nl = gn0 + l15; if (nl >= N) nl = N - 1;

    f32x4 a1[8], a2[8];
    #pragma unroll
    for (int nt = 0; nt < 8; ++nt) {
        a1[nt] = (f32x4){0.f, 0.f, 0.f, 0.f};
        a2[nt] = (f32x4){0.f, 0.f, 0.f, 0.f};
    }

    for (int kb = 0; kb < 4; ++kb) {
        int ko = kb * 32 + quad * 8;
        bf16x8 af = *(const bf16x8*)(hb + (size_t)nl * H + ko);
        const unsigned short* bp1 = eW1f + ((size_t)kb * 8) * 512 + (size_t)lane * 8;
        const unsigned short* bp2 = eW1f + ((size_t)(kb + 4) * 8) * 512 + (size_t)lane * 8;
        #pragma unroll
        for (int nt = 0; nt < 8; ++nt) {
            bf16x8 b1 = *(const bf16x8*)(bp1 + (size_t)nt * 512);
            bf16x8 b2 = *(const bf16x8*)(bp2 + (size_t)nt * 512);
            a1[nt] = __builtin_amdgcn_mfma_f32_16x16x32_bf16(af, b1, a1[nt], 0, 0, 0);
            a2[nt] = __builtin_amdgcn_mfma_f32_16x16x32_bf16(af, b2, a2[nt], 0, 0, 0);
        }
    }

    // C-layout -> LDS bf16 rows [node][256]
    #pragma unroll
    for (int nt = 0; nt < 8; ++nt) {
        int c = nt * 16 + l15;
        #pragma unroll
        for (int r = 0; r < 4; ++r) {
            int rr = quad * 4 + r;
            Y[rr * 256 + c]       = f2bf(a1[nt][r]);
            Y[rr * 256 + 128 + c] = f2bf(a2[nt][r]);
        }
    }

    // coalesced copy-out: 4 lanes per node, 8 x 16B each
    const int m = lane >> 2, part = lane & 3;
    int gm = gn0 + m; if (gm >= N) gm = N - 1;
    #pragma unroll
    for (int j = 0; j < 8; ++j) {
        uint4 v = *(const uint4*)&Y[m * 256 + part * 64 + j * 8];
        *(uint4*)(Pb + (size_t)gm * 256 + part * 64 + j * 8) = v;
    }
}

// ---- single-tile epilogue: bias + LN + SiLU; result in acc, bf16 copy in LDS X ----
__device__ __forceinline__ void ln_silu_store1(
    f32x4* acc, const float* __restrict__ bias, const float* __restrict__ g,
    const float* __restrict__ be, unsigned short* X, int l15, int quad)
{
    float s[4] = {0,0,0,0}, q[4] = {0,0,0,0};
    #pragma unroll
    for (int nt = 0; nt < 8; ++nt) {
        float b = bias[nt * 16 + l15];
        #pragma unroll
        for (int r = 0; r < 4; ++r) {
            float x = acc[nt][r] + b; acc[nt][r] = x; s[r] += x; q[r] += x * x;
        }
    }
    #pragma unroll
    for (int r = 0; r < 4; ++r) { s[r] = red16(s[r]); q[r] = red16(q[r]); }
    #pragma unroll
    for (int r = 0; r < 4; ++r) {
        float mu = s[r] * 0.0078125f, v = q[r] * 0.0078125f - mu * mu;
        s[r] = mu; q[r] = fast_rsq(v + 1e-5f);
    }
    #pragma unroll
    for (int nt = 0; nt < 8; ++nt) {
        float gg = g[nt * 16 + l15], bb = be[nt * 16 + l15];
        #pragma unroll
        for (int r = 0; r < 4; ++r) {
            float a = q[r] * gg, c = bb - s[r] * a;
            float y = silu_f(fmaf(acc[nt][r], a, c));
            acc[nt][r] = y;
            X[(quad * 4 + r) * XSTR + nt * 16 + l15] = f2bf(y);
        }
    }
}

// -------------------- edge kernel: 2 waves/block, 16 edges/wave --------------------
// Register-pressure law (rounds 4/5/6): unified VGPR+AGPR working set ≈ 120+; any
// launch_bounds budget < 128 spills ~50-180 MB to scratch HBM. So: budget 128
// (128,4). To push actual usage DOWN (occupancy is VGPR-limited now): LN1 stats
// (s,q) are computed during staging in gather layout (values die per-j, proven
// spill-free), bias folded in; epilogue 1 is a pure streaming transform of X with
// shuffled-in mu/rstd — the 32-float acc live range and 8x red16 are gone.
__global__ __launch_bounds__(128, 4) void edge_kernel(
    const unsigned short* __restrict__ Pb, const int* __restrict__ ei,
    const float* __restrict__ coord, const float* __restrict__ eattr,
    const float* __restrict__ eW1,
    const float* __restrict__ eb1, const float* __restrict__ eg1, const float* __restrict__ ebe1,
    const unsigned short* __restrict__ eW2f,
    const float* __restrict__ eb2, const float* __restrict__ eg2, const float* __restrict__ ebe2,
    const unsigned short* __restrict__ cW1f,
    const float* __restrict__ cb1, const float* __restrict__ cg1, const float* __restrict__ cbe1,
    const float* __restrict__ cW2,
    unsigned short* __restrict__ aggb, float* __restrict__ coord_out, int E)
{
    __shared__ unsigned short Xs[2][16 * XSTR];    // 4352 B per wave

    const int wv   = threadIdx.x >> 6;
    const int lane = threadIdx.x & 63;
    const int l15 = lane & 15, quad = lane >> 4;
    const int ge0 = (blockIdx.x * 2 + wv) * 16;
    unsigned short* X = &Xs[wv][0];

    if (ge0 >= E) return;

    int el  = ge0 + l15;
    int elc = (el < E) ? el : (E - 1);
    int rowl = ei[elc], coll = ei[E + elc];
    float dx = coord[rowl * 3 + 0] - coord[coll * 3 + 0];
    float dy = coord[rowl * 3 + 1] - coord[coll * 3 + 1];
    float dz = coord[rowl * 3 + 2] - coord[coll * 3 + 2];
    float radial = dx * dx + dy * dy + dz * dz;
    float inv = fast_rcp(fast_sqrt(radial + 1e-8f) + 1.0f);
    float cdx = dx * inv, cdy = dy * inv, cdz = dz * inv;
    float ea = eattr[elc];

    // ---- staging: P1[row]+P2[col]+rank-1+bias (fp32) -> bf16 X rows; s,q on the fly ----
    // lane (m = lane>>2, part = lane&3) owns cols [part*32, part*32+32) of edge m
    float mu, rstd;   // LN1 stats for edge m = lane>>2
    {
        const int m = lane >> 2, part = lane & 3;
        int row_m   = __shfl(rowl,   m, 64);
        int col_m   = __shfl(coll,   m, 64);
        float rad_m = __shfl(radial, m, 64);
        float ea_m  = __shfl(ea,     m, 64);
        const unsigned short* p1 = Pb + (size_t)row_m * 256 + part * 32;
        const unsigned short* p2 = Pb + (size_t)col_m * 256 + 128 + part * 32;
        const float* w6 = eW1 + 256 * H + part * 32;
        const float* w7 = eW1 + 257 * H + part * 32;
        const float* bp = eb1 + part * 32;
        unsigned short* Xrow = X + m * XSTR + part * 32;
        float s = 0.f, q = 0.f;
        #pragma unroll
        for (int j = 0; j < 4; ++j) {
            uint4 a = *(const uint4*)(p1 + j * 8);
            uint4 b = *(const uint4*)(p2 + j * 8);
            float4 wA = *(const float4*)(w6 + j * 8);
            float4 wB = *(const float4*)(w6 + j * 8 + 4);
            float4 uA = *(const float4*)(w7 + j * 8);
            float4 uB = *(const float4*)(w7 + j * 8 + 4);
            float4 bA = *(const float4*)(bp + j * 8);
            float4 bB = *(const float4*)(bp + j * 8 + 4);
            float v0 = bflo(a.x) + bflo(b.x) + rad_m * wA.x + ea_m * uA.x + bA.x;
            float v1 = bfhi(a.x) + bfhi(b.x) + rad_m * wA.y + ea_m * uA.y + bA.y;
            float v2 = bflo(a.y) + bflo(b.y) + rad_m * wA.z + ea_m * uA.z + bA.z;
            float v3 = bfhi(a.y) + bfhi(b.y) + rad_m * wA.w + ea_m * uA.w + bA.w;
            float v4 = bflo(a.z) + bflo(b.z) + rad_m * wB.x + ea_m * uB.x + bB.x;
            float v5 = bfhi(a.z) + bfhi(b.z) + rad_m * wB.y + ea_m * uB.y + bB.y;
            float v6 = bflo(a.w) + bflo(b.w) + rad_m * wB.z + ea_m * uB.z + bB.z;
            float v7 = bfhi(a.w) + bfhi(b.w) + rad_m * wB.w + ea_m * uB.w + bB.w;
            s += v0 + v1 + v2 + v3 + v4 + v5 + v6 + v7;
            q += v0 * v0 + v1 * v1 + v2 * v2 + v3 * v3
               + v4 * v4 + v5 * v5 + v6 * v6 + v7 * v7;
            uint4 o;
            o.x = pkbf(v0, v1); o.y = pkbf(v2, v3);
            o.z = pkbf(v4, v5); o.w = pkbf(v6, v7);
            *(uint4*)(Xrow + j * 8) = o;   // values die here: no spillable live range
        }
        // reduce across the 4 lanes of this edge (part = 0..3)
        s += __shfl_xor(s, 1, 64); s += __shfl_xor(s, 2, 64);
        q += __shfl_xor(q, 1, 64); q += __shfl_xor(q, 2, 64);
        mu   = s * 0.0078125f;
        rstd = fast_rsq(q * 0.0078125f - mu * mu + 1e-5f);
    }

    // ---- epilogue 1: streaming LN+SiLU over X in C-layout (no acc array) ----
    // each (row,col) element is read and rewritten by exactly one lane; same-wave
    // DS ordering makes staging writes visible and GEMM2 reads see these writes
    {
        float mur[4], rsr[4];
        #pragma unroll
        for (int r = 0; r < 4; ++r) {
            int src = (quad * 4 + r) << 2;     // any of the edge's 4 staging lanes
            mur[r] = __shfl(mu,   src, 64);
            rsr[r] = __shfl(rstd, src, 64);
        }
        #pragma unroll
        for (int nt = 0; nt < 8; ++nt) {
            float gg = eg1[nt * 16 + l15], bb = ebe1[nt * 16 + l15];
            #pragma unroll
            for (int r = 0; r < 4; ++r) {
                unsigned short* px = &X[(quad * 4 + r) * XSTR + nt * 16 + l15];
                float a = rsr[r] * gg, c = bb - mur[r] * a;
                float y = silu_f(fmaf(bfu(*px), a, c));
                *px = f2bf(y);
            }
        }
    }

    // ---- GEMM2: [16x128] @ eW2f ----
    f32x4 ac2[8];
    #pragma unroll
    for (int nt = 0; nt < 8; ++nt) ac2[nt] = (f32x4){0.f, 0.f, 0.f, 0.f};
    for (int kb = 0; kb < 4; ++kb) {
        bf16x8 af = *(const bf16x8*)&X[l15 * XSTR + kb * 32 + quad * 8];
        const unsigned short* bp = eW2f + ((size_t)kb * 8) * 512 + (size_t)lane * 8;
        #pragma unroll
        for (int nt = 0; nt < 8; ++nt) {
            bf16x8 bf = *(const bf16x8*)(bp + (size_t)nt * 512);
            ac2[nt] = __builtin_amdgcn_mfma_f32_16x16x32_bf16(af, bf, ac2[nt], 0, 0, 0);
        }
    }

    // ---- epilogue 2 = edge_feat -> X ----
    ln_silu_store1(ac2, eb2, eg2, ebe2, X, l15, quad);

    // ---- agg: packed-bf16 atomics, pairs read straight back from X ----
    {
        int rowm[4];
        #pragma unroll
        for (int r = 0; r < 4; ++r) rowm[r] = __shfl(rowl, quad * 4 + r, 64);
        #pragma unroll
        for (int c4 = 0; c4 < 4; ++c4) {
            #pragma unroll
            for (int r = 0; r < 4; ++r) {
                int geh = ge0 + quad * 4 + r;
                if (geh < E) {
                    unsigned int pkv =
                        *(const unsigned int*)&X[(quad * 4 + r) * XSTR + c4 * 32 + 2 * l15];
                    atomic_pk_add_bf16(aggb + (size_t)rowm[r] * H + c4 * 32 + 2 * l15, pkv);
                }
            }
        }
    }

    // ---- GEMM3: edge_feat @ cW1f ----
    f32x4 acc3[8];
    #pragma unroll
    for (int nt = 0; nt < 8; ++nt) acc3[nt] = (f32x4){0.f, 0.f, 0.f, 0.f};
    for (int kb = 0; kb < 4; ++kb) {
        bf16x8 af = *(const bf16x8*)&X[l15 * XSTR + kb * 32 + quad * 8];
        const unsigned short* bp = cW1f + ((size_t)kb * 8) * 512 + (size_t)lane * 8;
        #pragma unroll
        for (int nt = 0; nt < 8; ++nt) {
            bf16x8 bf = *(const bf16x8*)(bp + (size_t)nt * 512);
            acc3[nt] = __builtin_amdgcn_mfma_f32_16x16x32_bf16(af, bf, acc3[nt], 0, 0, 0);
        }
    }

    // ---- epilogue 3: bias + LN + SiLU, dot cW2 -> cm; coord atomics ----
    {
        float s[4] = {0,0,0,0}, q[4] = {0,0,0,0};
        #pragma unroll
        for (int nt = 0; nt < 8; ++nt) {
            float b = cb1[nt * 16 + l15];
            #pragma unroll
            for (int r = 0; r < 4; ++r) {
                float x = acc3[nt][r] + b; acc3[nt][r] = x; s[r] += x; q[r] += x * x;
            }
        }
        #pragma unroll
        for (int r = 0; r < 4; ++r) { s[r] = red16(s[r]); q[r] = red16(q[r]); }
        #pragma unroll
        for (int r = 0; r < 4; ++r) {
            float mu3 = s[r] * 0.0078125f, v = q[r] * 0.0078125f - mu3 * mu3;
            s[r] = mu3; q[r] = fast_rsq(v + 1e-5f);
        }
        float cm[4] = {0,0,0,0};
        #pragma unroll
        for (int nt = 0; nt < 8; ++nt) {
            float gg = cg1[nt * 16 + l15], bb = cbe1[nt * 16 + l15];
            float w2 = cW2[nt * 16 + l15];
            #pragma unroll
            for (int r = 0; r < 4; ++r) {
                float a = q[r] * gg, c = bb - s[r] * a;
                cm[r] += silu_f(fmaf(acc3[nt][r], a, c)) * w2;
            }
        }
        #pragma unroll
        for (int r = 0; r < 4; ++r) cm[r] = red16(cm[r]);
        #pragma unroll
        for (int r = 0; r < 4; ++r) {
            int src = quad * 4 + r;
            float cdxr = __shfl(cdx, src, 64);
            float cdyr = __shfl(cdy, src, 64);
            float cdzr = __shfl(cdz, src, 64);
            int rw = __shfl(rowl, src, 64);
            float comp = (l15 == 0) ? cdxr : ((l15 == 1) ? cdyr : cdzr);
            int geh = ge0 + src;
            if (l15 < 3 && geh < E)
                atomicAdd(&coord_out[(size_t)rw * 3 + l15], comp * cm[r]);
        }
    }
}

// ---- node kernel: 256 threads = 4 independent waves, 16 nodes each ----
__global__ __launch_bounds__(256, 4) void node_kernel(
    const unsigned short* __restrict__ hb, const float* __restrict__ h,
    const unsigned short* __restrict__ aggb,
    const unsigned short* __restrict__ nW1f,
    const float* __restrict__ nb1, const float* __restrict__ ng1, const float* __restrict__ nbe1,
    const unsigned short* __restrict__ nW2f, const float* __restrict__ nb2,
    float* __restrict__ out, int N)
{
    __shared__ unsigned short Xs[4][16 * XSTR];

    const int wv   = threadIdx.x >> 6;
    const int lane = threadIdx.x & 63;
    const int l15 = lane & 15, quad = lane >> 4;
    const int gn0 = (blockIdx.x * 4 + wv) * 16;
    unsigned short* X = &Xs[wv][0];

    if (gn0 >= N) return;
    int nl = gn0 + l15; if (nl >= N) nl = N - 1;

    f32x4 acc[8];
    #pragma unroll
    for (int nt = 0; nt < 8; ++nt) acc[nt] = (f32x4){0.f, 0.f, 0.f, 0.f};

    for (int kb = 0; kb < 8; ++kb) {
        int ko = (kb & 3) * 32 + quad * 8;
        const unsigned short* src = (kb < 4) ? hb : aggb;
        bf16x8 af = *(const bf16x8*)(src + (size_t)nl * H + ko);
        const unsigned short* bp = nW1f + ((size_t)kb * 8) * 512 + (size_t)lane * 8;
        #pragma unroll
        for (int nt = 0; nt < 8; ++nt) {
            bf16x8 bf = *(const bf16x8*)(bp + (size_t)nt * 512);
            acc[nt] = __builtin_amdgcn_mfma_f32_16x16x32_bf16(af, bf, acc[nt], 0, 0, 0);
        }
    }

    ln_silu_store1(acc, nb1, ng1, nbe1, X, l15, quad);

    f32x4 ac2[8];
    #pragma unroll
    for (int nt = 0; nt < 8; ++nt) ac2[nt] = (f32x4){0.f, 0.f, 0.f, 0.f};
    for (int kb = 0; kb < 4; ++kb) {
        bf16x8 af = *(const bf16x8*)&X[l15 * XSTR + kb * 32 + quad * 8];
        const unsigned short* bp = nW2f + ((size_t)kb * 8) * 512 + (size_t)lane * 8;
        #pragma unroll
        for (int nt = 0; nt < 8; ++nt) {
            bf16x8 bf = *(const bf16x8*)(bp + (size_t)nt * 512);
            ac2[nt] = __builtin_amdgcn_mfma_f32_16x16x32_bf16(af, bf, ac2[nt], 0, 0, 0);
        }
    }

    #pragma unroll
    for (int nt = 0; nt < 8; ++nt) {
        float b = nb2[nt * 16 + l15];
        #pragma unroll
        for (int r = 0; r < 4; ++r) {
            int gn = gn0 + quad * 4 + r;
            if (gn < N) {
                size_t idx = (size_t)gn * H + nt * 16 + l15;
                out[idx] = ac2[nt][r] + b + h[idx];
            }
        }
    }
}

// -------------------- launch --------------------
extern "C" void kernel_launch(void* const* d_in, const int* in_sizes, int n_in,
                              void* d_out, int out_size, void* d_ws, size_t ws_size,
                              hipStream_t stream) {
    const float* h     = (const float*)d_in[0];
    const int*   ei    = (const int*)d_in[1];
    const float* coord = (const float*)d_in[2];
    const float* eattr = (const float*)d_in[3];
    const float* eW1   = (const float*)d_in[4];
    const float* eb1   = (const float*)d_in[5];
    const float* eg1   = (const float*)d_in[6];
    const float* ebe1  = (const float*)d_in[7];
    const float* eW2   = (const float*)d_in[8];
    const float* eb2   = (const float*)d_in[9];
    const float* eg2   = (const float*)d_in[10];
    const float* ebe2  = (const float*)d_in[11];
    const float* nW1   = (const float*)d_in[12];
    const float* nb1   = (const float*)d_in[13];
    const float* ng1   = (const float*)d_in[14];
    const float* nbe1  = (const float*)d_in[15];
    const float* nW2   = (const float*)d_in[16];
    const float* nb2   = (const float*)d_in[17];
    const float* cW1   = (const float*)d_in[18];
    const float* cb1   = (const float*)d_in[19];
    const float* cg1   = (const float*)d_in[20];
    const float* cbe1  = (const float*)d_in[21];
    const float* cW2   = (const float*)d_in[22];

    const int N = in_sizes[0] / H;
    const int E = in_sizes[1] / 2;

    float* out       = (float*)d_out;
    float* coord_out = out + (size_t)N * H;

    // ---- workspace layout ----
    char* ws = (char*)d_ws;
    size_t o = 0;
    unsigned short* aggb = (unsigned short*)(ws + o); o += (size_t)N * H * 2;
    unsigned short* hb   = (unsigned short*)(ws + o); o += (size_t)N * H * 2;
    unsigned short* Pb   = (unsigned short*)(ws + o); o += (size_t)N * 256 * 2;
    unsigned short* eW1f = (unsigned short*)(ws + o); o += (size_t)H * KE * 2;
    unsigned short* eW2f = (unsigned short*)(ws + o); o += (size_t)H * H * 2;
    unsigned short* cW1f = (unsigned short*)(ws + o); o += (size_t)H * H * 2;
    unsigned short* nW1f = (unsigned short*)(ws + o); o += (size_t)H * KN * 2;
    unsigned short* nW2f = (unsigned short*)(ws + o); o += (size_t)H * H * 2;

    // ---- fused prep: hb | aggb zero | coord copy | weight frags ----
    const int n4_h   = N * H / 4;
    const int n4_agg = N * H / 8;          // 16B groups over N*H*2 bytes
    const int n_co   = N * 3;
    const int b0 = (n4_h   + 255) / 256;
    const int b1 = b0 + (n4_agg + 255) / 256;
    const int b2 = b1 + (n_co   + 255) / 256;
    const int bw = (4096 + 4096 + 2048 + 2048 + 2048 + 255) / 256;  // 56
    prep_all<<<b2 + bw, 256, 0, stream>>>(
        h, hb, n4_h, (float*)aggb, n4_agg, coord, coord_out, n_co,
        eW1, eW2, cW1, nW1, nW2,
        eW1f, eW2f, cW1f, nW1f, nW2f, b0, b1, b2);

    proj_kernel<<<(N + 63) / 64, 256, 0, stream>>>(hb, eW1f, Pb, N);

    edge_kernel<<<(E + 31) / 32, 128, 0, stream>>>(
        Pb, ei, coord, eattr,
        eW1, eb1, eg1, ebe1,
        eW2f, eb2, eg2, ebe2,
        cW1f, cb1, cg1, cbe1, cW2,
        aggb, coord_out, E);

    node_kernel<<<(N + 63) / 64, 256, 0, stream>>>(
        hb, h, aggb, nW1f, nb1, ng1, nbe1, nW2f, nb2, out, N);
}

// Round 8
// 316.181 us; speedup vs baseline: 1.0486x; 1.0486x over previous
//
#include <hip/hip_runtime.h>
#include <math.h>

#define H 128
#define KE 256      // eW1 MFMA K (k=256,257 via fp32 rank-1 update folded into staging)
#define KN 256      // node GEMM1 K (2H)
#define XSTR 136    // LDS X row stride (bf16 elems)
#define SSTR 132    // LDS S row stride (fp32 elems) — breaks 4-way bank alias

typedef __attribute__((ext_vector_type(8))) short bf16x8;
typedef __attribute__((ext_vector_type(4))) float f32x4;

__device__ __forceinline__ float fast_rcp(float x) {
#if defined(__has_builtin) && __has_builtin(__builtin_amdgcn_rcpf)
    return __builtin_amdgcn_rcpf(x);
#else
    return 1.0f / x;
#endif
}
__device__ __forceinline__ float fast_rsq(float x) {
#if defined(__has_builtin) && __has_builtin(__builtin_amdgcn_rsqf)
    return __builtin_amdgcn_rsqf(x);
#else
    return rsqrtf(x);
#endif
}
__device__ __forceinline__ float fast_sqrt(float x) {
#if defined(__has_builtin) && __has_builtin(__builtin_amdgcn_sqrtf)
    return __builtin_amdgcn_sqrtf(x);
#else
    return sqrtf(x);
#endif
}

// silu via v_rcp_f32 (1 ulp) instead of IEEE divide expansion (~10-14 VALU ops)
__device__ __forceinline__ float silu_f(float x) {
    return x * fast_rcp(1.0f + __expf(-x));
}

__device__ __forceinline__ unsigned short f2bf(float f) {
    unsigned int u = __float_as_uint(f);
    unsigned int r = u + 0x7FFFu + ((u >> 16) & 1u);
    return (unsigned short)(r >> 16);
}

__device__ __forceinline__ unsigned int pkbf(float a, float b) {
#if defined(__has_builtin)
#if __has_builtin(__builtin_amdgcn_cvt_pk_bf16_f32)
    typedef __attribute__((ext_vector_type(2))) __bf16 bf16x2_t;
    bf16x2_t v = __builtin_amdgcn_cvt_pk_bf16_f32(a, b);
    return *(unsigned int*)&v;
#else
    return (unsigned int)f2bf(a) | ((unsigned int)f2bf(b) << 16);
#endif
#else
    return (unsigned int)f2bf(a) | ((unsigned int)f2bf(b) << 16);
#endif
}

__device__ __forceinline__ float bflo(unsigned int w) { return __uint_as_float(w << 16); }
__device__ __forceinline__ float bfhi(unsigned int w) { return __uint_as_float(w & 0xFFFF0000u); }

// hardware packed-bf16 atomic add (gfx90a+/gfx950), fire-and-forget
__device__ __forceinline__ void atomic_pk_add_bf16(unsigned short* addr, unsigned int pkv) {
    asm volatile("global_atomic_pk_add_bf16 %0, %1, off"
                 :: "v"(addr), "v"(pkv) : "memory");
}

// ---- 16-lane sum reduction via DPP row rotations ----
template<int CTRL>
__device__ __forceinline__ float dpp_add(float x) {
    int t = __builtin_amdgcn_update_dpp(0, __float_as_int(x), CTRL, 0xF, 0xF, true);
    return x + __int_as_float(t);
}
__device__ __forceinline__ float red16(float x) {
    x = dpp_add<0x128>(x);
    x = dpp_add<0x124>(x);
    x = dpp_add<0x122>(x);
    x = dpp_add<0x121>(x);
    return x;
}

// ---- one weight fragment: W[K][128] fp32 -> fragment-linear Wf[f][8] bf16 ----
__device__ __forceinline__ void wfrag(const float* __restrict__ W,
                                      unsigned short* __restrict__ Wf, int f) {
    int kb = f >> 9, rem = f & 511;
    int nt = rem >> 6, lane = rem & 63;
    int quad = lane >> 4, l15 = lane & 15;
    int n = nt * 16 + l15, k0 = kb * 32 + quad * 8;
    union { bf16x8 v; unsigned short u[8]; } pk;
    #pragma unroll
    for (int j = 0; j < 8; ++j) pk.u[j] = f2bf(W[(size_t)(k0 + j) * H + n]);
    *(bf16x8*)&Wf[(size_t)f * 8] = pk.v;
}

// ---- fused prep: hb convert | aggb zero | coord copy | 5 weight transposes ----
__global__ __launch_bounds__(256) void prep_all(
    const float* __restrict__ h, unsigned short* __restrict__ hb, int n4_h,
    float* __restrict__ aggz, int n4_agg,
    const float* __restrict__ coord, float* __restrict__ coord_out, int n_coord,
    const float* __restrict__ eW1, const float* __restrict__ eW2,
    const float* __restrict__ cW1, const float* __restrict__ nW1,
    const float* __restrict__ nW2,
    unsigned short* __restrict__ eW1f, unsigned short* __restrict__ eW2f,
    unsigned short* __restrict__ cW1f, unsigned short* __restrict__ nW1f,
    unsigned short* __restrict__ nW2f,
    int b0, int b1, int b2)
{
    int b = blockIdx.x;
    int t = threadIdx.x;
    if (b < b0) {
        int i = b * 256 + t;
        if (i < n4_h) {
            float4 f = ((const float4*)h)[i];
            ((uint2*)hb)[i] = make_uint2(pkbf(f.x, f.y), pkbf(f.z, f.w));
        }
    } else if (b < b1) {
        int i = (b - b0) * 256 + t;
        if (i < n4_agg) ((float4*)aggz)[i] = (float4){0.f, 0.f, 0.f, 0.f};
    } else if (b < b2) {
        int i = (b - b1) * 256 + t;
        if (i < n_coord) coord_out[i] = coord[i];
    } else {
        int idx = (b - b2) * 256 + t;
        if      (idx <  4096) wfrag(eW1, eW1f, idx);
        else if (idx <  8192) wfrag(nW1, nW1f, idx - 4096);
        else if (idx < 10240) wfrag(eW2, eW2f, idx - 8192);
        else if (idx < 12288) wfrag(cW1, cW1f, idx - 10240);
        else if (idx < 14336) wfrag(nW2, nW2f, idx - 12288);
    }
}

// ---- proj kernel: Pb[n][0:128] = h[n]@eW1[0:128,:], Pb[n][128:256] = h[n]@eW1[128:256,:]
__global__ __launch_bounds__(256, 4) void proj_kernel(
    const unsigned short* __restrict__ hb,
    const unsigned short* __restrict__ eW1f,
    unsigned short* __restrict__ Pb, int N)
{
    __shared__ unsigned short Ys[4][16 * 256];   // 8 KB per wave

    const int wv = threadIdx.x >> 6;
    const int lane = threadIdx.x & 63;
    const int l15 = lane & 15, quad = lane >> 4;
    const int gn0 = (blockIdx.x * 4 + wv) * 16;
    unsigned short* Y = &Ys[wv][0];

    if (gn0 >= N) return;
    int nl = gn0 + l15; if (nl >= N) nl = N - 1;

    f32x4 a1[8], a2[8];
    #pragma unroll
    for (int nt = 0; nt < 8; ++nt) {
        a1[nt] = (f32x4){0.f, 0.f, 0.f, 0.f};
        a2[nt] = (f32x4){0.f, 0.f, 0.f, 0.f};
    }

    for (int kb = 0; kb < 4; ++kb) {
        int ko = kb * 32 + quad * 8;
        bf16x8 af = *(const bf16x8*)(hb + (size_t)nl * H + ko);
        const unsigned short* bp1 = eW1f + ((size_t)kb * 8) * 512 + (size_t)lane * 8;
        const unsigned short* bp2 = eW1f + ((size_t)(kb + 4) * 8) * 512 + (size_t)lane * 8;
        #pragma unroll
        for (int nt = 0; nt < 8; ++nt) {
            bf16x8 b1 = *(const bf16x8*)(bp1 + (size_t)nt * 512);
            bf16x8 b2 = *(const bf16x8*)(bp2 + (size_t)nt * 512);
            a1[nt] = __builtin_amdgcn_mfma_f32_16x16x32_bf16(af, b1, a1[nt], 0, 0, 0);
            a2[nt] = __builtin_amdgcn_mfma_f32_16x16x32_bf16(af, b2, a2[nt], 0, 0, 0);
        }
    }

    // C-layout -> LDS bf16 rows [node][256]
    #pragma unroll
    for (int nt = 0; nt < 8; ++nt) {
        int c = nt * 16 + l15;
        #pragma unroll
        for (int r = 0; r < 4; ++r) {
            int rr = quad * 4 + r;
            Y[rr * 256 + c]       = f2bf(a1[nt][r]);
            Y[rr * 256 + 128 + c] = f2bf(a2[nt][r]);
        }
    }

    // coalesced copy-out: 4 lanes per node, 8 x 16B each
    const int m = lane >> 2, part = lane & 3;
    int gm = gn0 + m; if (gm >= N) gm = N - 1;
    #pragma unroll
    for (int j = 0; j < 8; ++j) {
        uint4 v = *(const uint4*)&Y[m * 256 + part * 64 + j * 8];
        *(uint4*)(Pb + (size_t)gm * 256 + part * 64 + j * 8) = v;
    }
}

// ---- single-tile epilogue: bias + LN + SiLU; result in acc, bf16 copy in LDS X ----
__device__ __forceinline__ void ln_silu_store1(
    f32x4* acc, const float* __restrict__ bias, const float* __restrict__ g,
    const float* __restrict__ be, unsigned short* X, int l15, int quad)
{
    float s[4] = {0,0,0,0}, q[4] = {0,0,0,0};
    #pragma unroll
    for (int nt = 0; nt < 8; ++nt) {
        float b = bias[nt * 16 + l15];
        #pragma unroll
        for (int r = 0; r < 4; ++r) {
            float x = acc[nt][r] + b; acc[nt][r] = x; s[r] += x; q[r] += x * x;
        }
    }
    #pragma unroll
    for (int r = 0; r < 4; ++r) { s[r] = red16(s[r]); q[r] = red16(q[r]); }
    #pragma unroll
    for (int r = 0; r < 4; ++r) {
        float mu = s[r] * 0.0078125f, v = q[r] * 0.0078125f - mu * mu;
        s[r] = mu; q[r] = fast_rsq(v + 1e-5f);
    }
    #pragma unroll
    for (int nt = 0; nt < 8; ++nt) {
        float gg = g[nt * 16 + l15], bb = be[nt * 16 + l15];
        #pragma unroll
        for (int r = 0; r < 4; ++r) {
            float a = q[r] * gg, c = bb - s[r] * a;
            float y = silu_f(fmaf(acc[nt][r], a, c));
            acc[nt][r] = y;
            X[(quad * 4 + r) * XSTR + nt * 16 + l15] = f2bf(y);
        }
    }
}

// -------------------- edge kernel: 1 wave, 16 edges (R4 structure + fused LN1 stats) ----
// R4's proven schedule (fp32 S staging, C-layout register read, single X write) with
// epilogue-1's redundant VALU deleted: rank-1+bias fold into staging (vectorized
// float4 loads, values die per-j — spill-free pattern), s/q accumulate during
// staging, 2x shfl_xor + 8 broadcast shuffles replace 8x red16 + bias pass.
__global__ __launch_bounds__(64, 4) void edge_kernel(
    const unsigned short* __restrict__ Pb, const int* __restrict__ ei,
    const float* __restrict__ coord, const float* __restrict__ eattr,
    const float* __restrict__ eW1,
    const float* __restrict__ eb1, const float* __restrict__ eg1, const float* __restrict__ ebe1,
    const unsigned short* __restrict__ eW2f,
    const float* __restrict__ eb2, const float* __restrict__ eg2, const float* __restrict__ ebe2,
    const unsigned short* __restrict__ cW1f,
    const float* __restrict__ cb1, const float* __restrict__ cg1, const float* __restrict__ cbe1,
    const float* __restrict__ cW2,
    unsigned short* __restrict__ aggb, float* __restrict__ coord_out, int E)
{
    __shared__ float S[16 * SSTR];                 // 8448 B; X aliases S
    unsigned short* X = (unsigned short*)S;

    const int lane = threadIdx.x;
    const int l15 = lane & 15, quad = lane >> 4;
    const int ge0 = blockIdx.x * 16;

    int el  = ge0 + l15;
    int elc = (el < E) ? el : (E - 1);
    int rowl = ei[elc], coll = ei[E + elc];
    float dx = coord[rowl * 3 + 0] - coord[coll * 3 + 0];
    float dy = coord[rowl * 3 + 1] - coord[coll * 3 + 1];
    float dz = coord[rowl * 3 + 2] - coord[coll * 3 + 2];
    float radial = dx * dx + dy * dy + dz * dz;
    float inv = fast_rcp(fast_sqrt(radial + 1e-8f) + 1.0f);
    float cdx = dx * inv, cdy = dy * inv, cdz = dz * inv;
    float ea = eattr[elc];

    // ---- staging: P1[row]+P2[col]+rank-1+bias (fp32) -> S; s,q on the fly ----
    // lane (m = lane>>2, part = lane&3) owns cols [part*32, part*32+32) of edge m
    float mu, rstd;   // LN1 stats for edge m = lane>>2
    {
        const int m = lane >> 2, part = lane & 3;
        int row_m   = __shfl(rowl,   m, 64);
        int col_m   = __shfl(coll,   m, 64);
        float rad_m = __shfl(radial, m, 64);
        float ea_m  = __shfl(ea,     m, 64);
        const unsigned short* p1 = Pb + (size_t)row_m * 256 + part * 32;
        const unsigned short* p2 = Pb + (size_t)col_m * 256 + 128 + part * 32;
        const float* w6 = eW1 + 256 * H + part * 32;
        const float* w7 = eW1 + 257 * H + part * 32;
        const float* bp = eb1 + part * 32;
        float* Srow = &S[m * SSTR + part * 32];
        float s = 0.f, q = 0.f;
        #pragma unroll
        for (int j = 0; j < 4; ++j) {
            uint4 a = *(const uint4*)(p1 + j * 8);
            uint4 b = *(const uint4*)(p2 + j * 8);
            float4 wA = *(const float4*)(w6 + j * 8);
            float4 wB = *(const float4*)(w6 + j * 8 + 4);
            float4 uA = *(const float4*)(w7 + j * 8);
            float4 uB = *(const float4*)(w7 + j * 8 + 4);
            float4 bA = *(const float4*)(bp + j * 8);
            float4 bB = *(const float4*)(bp + j * 8 + 4);
            float4 v0, v1;
            v0.x = bflo(a.x) + bflo(b.x) + rad_m * wA.x + ea_m * uA.x + bA.x;
            v0.y = bfhi(a.x) + bfhi(b.x) + rad_m * wA.y + ea_m * uA.y + bA.y;
            v0.z = bflo(a.y) + bflo(b.y) + rad_m * wA.z + ea_m * uA.z + bA.z;
            v0.w = bfhi(a.y) + bfhi(b.y) + rad_m * wA.w + ea_m * uA.w + bA.w;
            v1.x = bflo(a.z) + bflo(b.z) + rad_m * wB.x + ea_m * uB.x + bB.x;
            v1.y = bfhi(a.z) + bfhi(b.z) + rad_m * wB.y + ea_m * uB.y + bB.y;
            v1.z = bflo(a.w) + bflo(b.w) + rad_m * wB.z + ea_m * uB.z + bB.z;
            v1.w = bfhi(a.w) + bfhi(b.w) + rad_m * wB.w + ea_m * uB.w + bB.w;
            s += v0.x + v0.y + v0.z + v0.w + v1.x + v1.y + v1.z + v1.w;
            q += v0.x * v0.x + v0.y * v0.y + v0.z * v0.z + v0.w * v0.w
               + v1.x * v1.x + v1.y * v1.y + v1.z * v1.z + v1.w * v1.w;
            *(float4*)(Srow + j * 8)     = v0;
            *(float4*)(Srow + j * 8 + 4) = v1;   // values die here per-j
        }
        // reduce across the 4 lanes of this edge (part = 0..3)
        s += __shfl_xor(s, 1, 64); s += __shfl_xor(s, 2, 64);
        q += __shfl_xor(q, 1, 64); q += __shfl_xor(q, 2, 64);
        mu   = s * 0.0078125f;
        rstd = fast_rsq(q * 0.0078125f - mu * mu + 1e-5f);
    }

    // ---- epilogue 1: C-layout read of S into registers (R4 pattern), then
    //      LN+SiLU with broadcast stats, single X write. X aliases S: all S
    //      reads complete (in-wave DS order) before any X write issues. ----
    f32x4 acc[8];
    #pragma unroll
    for (int nt = 0; nt < 8; ++nt) {
        #pragma unroll
        for (int r = 0; r < 4; ++r)
            acc[nt][r] = S[(quad * 4 + r) * SSTR + nt * 16 + l15];
    }
    asm volatile("" ::: "memory");   // pin read-before-write across the alias
    {
        float mur[4], rsr[4];
        #pragma unroll
        for (int r = 0; r < 4; ++r) {
            int src = (quad * 4 + r) << 2;     // any of the edge's 4 staging lanes
            mur[r] = __shfl(mu,   src, 64);
            rsr[r] = __shfl(rstd, src, 64);
        }
        #pragma unroll
        for (int nt = 0; nt < 8; ++nt) {
            float gg = eg1[nt * 16 + l15], bb = ebe1[nt * 16 + l15];
            #pragma unroll
            for (int r = 0; r < 4; ++r) {
                float a = rsr[r] * gg, c = bb - mur[r] * a;
                float y = silu_f(fmaf(acc[nt][r], a, c));
                X[(quad * 4 + r) * XSTR + nt * 16 + l15] = f2bf(y);
            }
        }
    }

    // ---- GEMM2: [16x128] @ eW2f ----
    f32x4 ac2[8];
    #pragma unroll
    for (int nt = 0; nt < 8; ++nt) ac2[nt] = (f32x4){0.f, 0.f, 0.f, 0.f};
    for (int kb = 0; kb < 4; ++kb) {
        bf16x8 af = *(const bf16x8*)&X[l15 * XSTR + kb * 32 + quad * 8];
        const unsigned short* bp = eW2f + ((size_t)kb * 8) * 512 + (size_t)lane * 8;
        #pragma unroll
        for (int nt = 0; nt < 8; ++nt) {
            bf16x8 bf = *(const bf16x8*)(bp + (size_t)nt * 512);
            ac2[nt] = __builtin_amdgcn_mfma_f32_16x16x32_bf16(af, bf, ac2[nt], 0, 0, 0);
        }
    }

    // ---- epilogue 2 = edge_feat -> X ----
    ln_silu_store1(ac2, eb2, eg2, ebe2, X, l15, quad);

    // ---- agg: packed-bf16 atomics, pairs read straight back from X (R11 pattern) ----
    {
        int rowm[4];
        #pragma unroll
        for (int r = 0; r < 4; ++r) rowm[r] = __shfl(rowl, quad * 4 + r, 64);
        #pragma unroll
        for (int c4 = 0; c4 < 4; ++c4) {
            #pragma unroll
            for (int r = 0; r < 4; ++r) {
                int geh = ge0 + quad * 4 + r;
                if (geh < E) {
                    unsigned int pkv =
                        *(const unsigned int*)&X[(quad * 4 + r) * XSTR + c4 * 32 + 2 * l15];
                    atomic_pk_add_bf16(aggb + (size_t)rowm[r] * H + c4 * 32 + 2 * l15, pkv);
                }
            }
        }
    }

    // ---- GEMM3: edge_feat @ cW1f ----
    f32x4 acc3[8];
    #pragma unroll
    for (int nt = 0; nt < 8; ++nt) acc3[nt] = (f32x4){0.f, 0.f, 0.f, 0.f};
    for (int kb = 0; kb < 4; ++kb) {
        bf16x8 af = *(const bf16x8*)&X[l15 * XSTR + kb * 32 + quad * 8];
        const unsigned short* bp = cW1f + ((size_t)kb * 8) * 512 + (size_t)lane * 8;
        #pragma unroll
        for (int nt = 0; nt < 8; ++nt) {
            bf16x8 bf = *(const bf16x8*)(bp + (size_t)nt * 512);
            acc3[nt] = __builtin_amdgcn_mfma_f32_16x16x32_bf16(af, bf, acc3[nt], 0, 0, 0);
        }
    }

    // ---- epilogue 3: bias + LN + SiLU, dot cW2 -> cm; coord atomics ----
    {
        float s[4] = {0,0,0,0}, q[4] = {0,0,0,0};
        #pragma unroll
        for (int nt = 0; nt < 8; ++nt) {
            float b = cb1[nt * 16 + l15];
            #pragma unroll
            for (int r = 0; r < 4; ++r) {
                float x = acc3[nt][r] + b; acc3[nt][r] = x; s[r] += x; q[r] += x * x;
            }
        }
        #pragma unroll
        for (int r = 0; r < 4; ++r) { s[r] = red16(s[r]); q[r] = red16(q[r]); }
        #pragma unroll
        for (int r = 0; r < 4; ++r) {
            float mu3 = s[r] * 0.0078125f, v = q[r] * 0.0078125f - mu3 * mu3;
            s[r] = mu3; q[r] = fast_rsq(v + 1e-5f);
        }
        float cm[4] = {0,0,0,0};
        #pragma unroll
        for (int nt = 0; nt < 8; ++nt) {
            float gg = cg1[nt * 16 + l15], bb = cbe1[nt * 16 + l15];
            float w2 = cW2[nt * 16 + l15];
            #pragma unroll
            for (int r = 0; r < 4; ++r) {
                float a = q[r] * gg, c = bb - s[r] * a;
                cm[r] += silu_f(fmaf(acc3[nt][r], a, c)) * w2;
            }
        }
        #pragma unroll
        for (int r = 0; r < 4; ++r) cm[r] = red16(cm[r]);
        #pragma unroll
        for (int r = 0; r < 4; ++r) {
            int src = quad * 4 + r;
            float cdxr = __shfl(cdx, src, 64);
            float cdyr = __shfl(cdy, src, 64);
            float cdzr = __shfl(cdz, src, 64);
            int rw = __shfl(rowl, src, 64);
            float comp = (l15 == 0) ? cdxr : ((l15 == 1) ? cdyr : cdzr);
            int geh = ge0 + src;
            if (l15 < 3 && geh < E)
                atomicAdd(&coord_out[(size_t)rw * 3 + l15], comp * cm[r]);
        }
    }
}

// ---- node kernel: 256 threads = 4 independent waves, 16 nodes each ----
__global__ __launch_bounds__(256, 4) void node_kernel(
    const unsigned short* __restrict__ hb, const float* __restrict__ h,
    const unsigned short* __restrict__ aggb,
    const unsigned short* __restrict__ nW1f,
    const float* __restrict__ nb1, const float* __restrict__ ng1, const float* __restrict__ nbe1,
    const unsigned short* __restrict__ nW2f, const float* __restrict__ nb2,
    float* __restrict__ out, int N)
{
    __shared__ unsigned short Xs[4][16 * XSTR];

    const int wv   = threadIdx.x >> 6;
    const int lane = threadIdx.x & 63;
    const int l15 = lane & 15, quad = lane >> 4;
    const int gn0 = (blockIdx.x * 4 + wv) * 16;
    unsigned short* X = &Xs[wv][0];

    if (gn0 >= N) return;
    int nl = gn0 + l15; if (nl >= N) nl = N - 1;

    f32x4 acc[8];
    #pragma unroll
    for (int nt = 0; nt < 8; ++nt) acc[nt] = (f32x4){0.f, 0.f, 0.f, 0.f};

    for (int kb = 0; kb < 8; ++kb) {
        int ko = (kb & 3) * 32 + quad * 8;
        const unsigned short* src = (kb < 4) ? hb : aggb;
        bf16x8 af = *(const bf16x8*)(src + (size_t)nl * H + ko);
        const unsigned short* bp = nW1f + ((size_t)kb * 8) * 512 + (size_t)lane * 8;
        #pragma unroll
        for (int nt = 0; nt < 8; ++nt) {
            bf16x8 bf = *(const bf16x8*)(bp + (size_t)nt * 512);
            acc[nt] = __builtin_amdgcn_mfma_f32_16x16x32_bf16(af, bf, acc[nt], 0, 0, 0);
        }
    }

    ln_silu_store1(acc, nb1, ng1, nbe1, X, l15, quad);

    f32x4 ac2[8];
    #pragma unroll
    for (int nt = 0; nt < 8; ++nt) ac2[nt] = (f32x4){0.f, 0.f, 0.f, 0.f};
    for (int kb = 0; kb < 4; ++kb) {
        bf16x8 af = *(const bf16x8*)&X[l15 * XSTR + kb * 32 + quad * 8];
        const unsigned short* bp = nW2f + ((size_t)kb * 8) * 512 + (size_t)lane * 8;
        #pragma unroll
        for (int nt = 0; nt < 8; ++nt) {
            bf16x8 bf = *(const bf16x8*)(bp + (size_t)nt * 512);
            ac2[nt] = __builtin_amdgcn_mfma_f32_16x16x32_bf16(af, bf, ac2[nt], 0, 0, 0);
        }
    }

    #pragma unroll
    for (int nt = 0; nt < 8; ++nt) {
        float b = nb2[nt * 16 + l15];
        #pragma unroll
        for (int r = 0; r < 4; ++r) {
            int gn = gn0 + quad * 4 + r;
            if (gn < N) {
                size_t idx = (size_t)gn * H + nt * 16 + l15;
                out[idx] = ac2[nt][r] + b + h[idx];
            }
        }
    }
}

// -------------------- launch --------------------
extern "C" void kernel_launch(void* const* d_in, const int* in_sizes, int n_in,
                              void* d_out, int out_size, void* d_ws, size_t ws_size,
                              hipStream_t stream) {
    const float* h     = (const float*)d_in[0];
    const int*   ei    = (const int*)d_in[1];
    const float* coord = (const float*)d_in[2];
    const float* eattr = (const float*)d_in[3];
    const float* eW1   = (const float*)d_in[4];
    const float* eb1   = (const float*)d_in[5];
    const float* eg1   = (const float*)d_in[6];
    const float* ebe1  = (const float*)d_in[7];
    const float* eW2   = (const float*)d_in[8];
    const float* eb2   = (const float*)d_in[9];
    const float* eg2   = (const float*)d_in[10];
    const float* ebe2  = (const float*)d_in[11];
    const float* nW1   = (const float*)d_in[12];
    const float* nb1   = (const float*)d_in[13];
    const float* ng1   = (const float*)d_in[14];
    const float* nbe1  = (const float*)d_in[15];
    const float* nW2   = (const float*)d_in[16];
    const float* nb2   = (const float*)d_in[17];
    const float* cW1   = (const float*)d_in[18];
    const float* cb1   = (const float*)d_in[19];
    const float* cg1   = (const float*)d_in[20];
    const float* cbe1  = (const float*)d_in[21];
    const float* cW2   = (const float*)d_in[22];

    const int N = in_sizes[0] / H;
    const int E = in_sizes[1] / 2;

    float* out       = (float*)d_out;
    float* coord_out = out + (size_t)N * H;

    // ---- workspace layout ----
    char* ws = (char*)d_ws;
    size_t o = 0;
    unsigned short* aggb = (unsigned short*)(ws + o); o += (size_t)N * H * 2;
    unsigned short* hb   = (unsigned short*)(ws + o); o += (size_t)N * H * 2;
    unsigned short* Pb   = (unsigned short*)(ws + o); o += (size_t)N * 256 * 2;
    unsigned short* eW1f = (unsigned short*)(ws + o); o += (size_t)H * KE * 2;
    unsigned short* eW2f = (unsigned short*)(ws + o); o += (size_t)H * H * 2;
    unsigned short* cW1f = (unsigned short*)(ws + o); o += (size_t)H * H * 2;
    unsigned short* nW1f = (unsigned short*)(ws + o); o += (size_t)H * KN * 2;
    unsigned short* nW2f = (unsigned short*)(ws + o); o += (size_t)H * H * 2;

    // ---- fused prep: hb | aggb zero | coord copy | weight frags ----
    const int n4_h   = N * H / 4;
    const int n4_agg = N * H / 8;          // 16B groups over N*H*2 bytes
    const int n_co   = N * 3;
    const int b0 = (n4_h   + 255) / 256;
    const int b1 = b0 + (n4_agg + 255) / 256;
    const int b2 = b1 + (n_co   + 255) / 256;
    const int bw = (4096 + 4096 + 2048 + 2048 + 2048 + 255) / 256;  // 56
    prep_all<<<b2 + bw, 256, 0, stream>>>(
        h, hb, n4_h, (float*)aggb, n4_agg, coord, coord_out, n_co,
        eW1, eW2, cW1, nW1, nW2,
        eW1f, eW2f, cW1f, nW1f, nW2f, b0, b1, b2);

    proj_kernel<<<(N + 63) / 64, 256, 0, stream>>>(hb, eW1f, Pb, N);

    edge_kernel<<<(E + 15) / 16, 64, 0, stream>>>(
        Pb, ei, coord, eattr,
        eW1, eb1, eg1, ebe1,
        eW2f, eb2, eg2, ebe2,
        cW1f, cb1, cg1, cbe1, cW2,
        aggb, coord_out, E);

    node_kernel<<<(N + 63) / 64, 256, 0, stream>>>(
        hb, h, aggb, nW1f, nb1, ng1, nbe1, nW2f, nb2, out, N);
}

// Round 10
// 292.631 us; speedup vs baseline: 1.1329x; 1.0805x over previous
//
#include <hip/hip_runtime.h>
#include <math.h>

#define H 128
#define KE 256      // eW1 MFMA K (k=256,257 via fp32 rank-1 update)
#define KN 256      // node GEMM1 K (2H)
#define XSTR 136    // LDS X row stride (bf16 elems)
#define SSTR 132    // LDS S row stride (fp32 elems) — breaks 4-way bank alias

typedef __attribute__((ext_vector_type(8))) short bf16x8;
typedef __attribute__((ext_vector_type(4))) float f32x4;

__device__ __forceinline__ float fast_rcp(float x) {
#if defined(__has_builtin) && __has_builtin(__builtin_amdgcn_rcpf)
    return __builtin_amdgcn_rcpf(x);
#else
    return 1.0f / x;
#endif
}
__device__ __forceinline__ float fast_rsq(float x) {
#if defined(__has_builtin) && __has_builtin(__builtin_amdgcn_rsqf)
    return __builtin_amdgcn_rsqf(x);
#else
    return rsqrtf(x);
#endif
}
__device__ __forceinline__ float fast_sqrt(float x) {
#if defined(__has_builtin) && __has_builtin(__builtin_amdgcn_sqrtf)
    return __builtin_amdgcn_sqrtf(x);
#else
    return sqrtf(x);
#endif
}

// silu via v_rcp_f32 (1 ulp) instead of IEEE divide expansion (~10-14 VALU ops)
__device__ __forceinline__ float silu_f(float x) {
    return x * fast_rcp(1.0f + __expf(-x));
}

__device__ __forceinline__ unsigned short f2bf(float f) {
    unsigned int u = __float_as_uint(f);
    unsigned int r = u + 0x7FFFu + ((u >> 16) & 1u);
    return (unsigned short)(r >> 16);
}

__device__ __forceinline__ unsigned int pkbf(float a, float b) {
#if defined(__has_builtin)
#if __has_builtin(__builtin_amdgcn_cvt_pk_bf16_f32)
    typedef __attribute__((ext_vector_type(2))) __bf16 bf16x2_t;
    bf16x2_t v = __builtin_amdgcn_cvt_pk_bf16_f32(a, b);
    return *(unsigned int*)&v;
#else
    return (unsigned int)f2bf(a) | ((unsigned int)f2bf(b) << 16);
#endif
#else
    return (unsigned int)f2bf(a) | ((unsigned int)f2bf(b) << 16);
#endif
}

__device__ __forceinline__ float bflo(unsigned int w) { return __uint_as_float(w << 16); }
__device__ __forceinline__ float bfhi(unsigned int w) { return __uint_as_float(w & 0xFFFF0000u); }

// hardware packed-bf16 atomic add (gfx90a+/gfx950), fire-and-forget
__device__ __forceinline__ void atomic_pk_add_bf16(unsigned short* addr, unsigned int pkv) {
    asm volatile("global_atomic_pk_add_bf16 %0, %1, off"
                 :: "v"(addr), "v"(pkv) : "memory");
}

// ---- 16-lane sum reduction via DPP row rotations ----
template<int CTRL>
__device__ __forceinline__ float dpp_add(float x) {
    int t = __builtin_amdgcn_update_dpp(0, __float_as_int(x), CTRL, 0xF, 0xF, true);
    return x + __int_as_float(t);
}
__device__ __forceinline__ float red16(float x) {
    x = dpp_add<0x128>(x);
    x = dpp_add<0x124>(x);
    x = dpp_add<0x122>(x);
    x = dpp_add<0x121>(x);
    return x;
}

// ---- one weight fragment: W[K][128] fp32 -> fragment-linear Wf[f][8] bf16 ----
__device__ __forceinline__ void wfrag(const float* __restrict__ W,
                                      unsigned short* __restrict__ Wf, int f) {
    int kb = f >> 9, rem = f & 511;
    int nt = rem >> 6, lane = rem & 63;
    int quad = lane >> 4, l15 = lane & 15;
    int n = nt * 16 + l15, k0 = kb * 32 + quad * 8;
    union { bf16x8 v; unsigned short u[8]; } pk;
    #pragma unroll
    for (int j = 0; j < 8; ++j) pk.u[j] = f2bf(W[(size_t)(k0 + j) * H + n]);
    *(bf16x8*)&Wf[(size_t)f * 8] = pk.v;
}

// ---- fused prep: hb convert | aggb zero | coord copy | 5 weight transposes ----
__global__ __launch_bounds__(256) void prep_all(
    const float* __restrict__ h, unsigned short* __restrict__ hb, int n4_h,
    float* __restrict__ aggz, int n4_agg,
    const float* __restrict__ coord, float* __restrict__ coord_out, int n_coord,
    const float* __restrict__ eW1, const float* __restrict__ eW2,
    const float* __restrict__ cW1, const float* __restrict__ nW1,
    const float* __restrict__ nW2,
    unsigned short* __restrict__ eW1f, unsigned short* __restrict__ eW2f,
    unsigned short* __restrict__ cW1f, unsigned short* __restrict__ nW1f,
    unsigned short* __restrict__ nW2f,
    int b0, int b1, int b2)
{
    int b = blockIdx.x;
    int t = threadIdx.x;
    if (b < b0) {
        int i = b * 256 + t;
        if (i < n4_h) {
            float4 f = ((const float4*)h)[i];
            ((uint2*)hb)[i] = make_uint2(pkbf(f.x, f.y), pkbf(f.z, f.w));
        }
    } else if (b < b1) {
        int i = (b - b0) * 256 + t;
        if (i < n4_agg) ((float4*)aggz)[i] = (float4){0.f, 0.f, 0.f, 0.f};
    } else if (b < b2) {
        int i = (b - b1) * 256 + t;
        if (i < n_coord) coord_out[i] = coord[i];
    } else {
        int idx = (b - b2) * 256 + t;
        if      (idx <  4096) wfrag(eW1, eW1f, idx);
        else if (idx <  8192) wfrag(nW1, nW1f, idx - 4096);
        else if (idx < 10240) wfrag(eW2, eW2f, idx - 8192);
        else if (idx < 12288) wfrag(cW1, cW1f, idx - 10240);
        else if (idx < 14336) wfrag(nW2, nW2f, idx - 12288);
    }
}

// ---- proj kernel: Pb[n][0:128] = h[n]@eW1[0:128,:], Pb[n][128:256] = h[n]@eW1[128:256,:]
__global__ __launch_bounds__(256, 4) void proj_kernel(
    const unsigned short* __restrict__ hb,
    const unsigned short* __restrict__ eW1f,
    unsigned short* __restrict__ Pb, int N)
{
    __shared__ unsigned short Ys[4][16 * 256];   // 8 KB per wave

    const int wv = threadIdx.x >> 6;
    const int lane = threadIdx.x & 63;
    const int l15 = lane & 15, quad = lane >> 4;
    const int gn0 = (blockIdx.x * 4 + wv) * 16;
    unsigned short* Y = &Ys[wv][0];

    if (gn0 >= N) return;
    int nl = gn0 + l15; if (nl >= N) nl = N - 1;

    f32x4 a1[8], a2[8];
    #pragma unroll
    for (int nt = 0; nt < 8; ++nt) {
        a1[nt] = (f32x4){0.f, 0.f, 0.f, 0.f};
        a2[nt] = (f32x4){0.f, 0.f, 0.f, 0.f};
    }

    for (int kb = 0; kb < 4; ++kb) {
        int ko = kb * 32 + quad * 8;
        bf16x8 af = *(const bf16x8*)(hb + (size_t)nl * H + ko);
        const unsigned short* bp1 = eW1f + ((size_t)kb * 8) * 512 + (size_t)lane * 8;
        const unsigned short* bp2 = eW1f + ((size_t)(kb + 4) * 8) * 512 + (size_t)lane * 8;
        #pragma unroll
        for (int nt = 0; nt < 8; ++nt) {
            bf16x8 b1 = *(const bf16x8*)(bp1 + (size_t)nt * 512);
            bf16x8 b2 = *(const bf16x8*)(bp2 + (size_t)nt * 512);
            a1[nt] = __builtin_amdgcn_mfma_f32_16x16x32_bf16(af, b1, a1[nt], 0, 0, 0);
            a2[nt] = __builtin_amdgcn_mfma_f32_16x16x32_bf16(af, b2, a2[nt], 0, 0, 0);
        }
    }

    // C-layout -> LDS bf16 rows [node][256]
    #pragma unroll
    for (int nt = 0; nt < 8; ++nt) {
        int c = nt * 16 + l15;
        #pragma unroll
        for (int r = 0; r < 4; ++r) {
            int rr = quad * 4 + r;
            Y[rr * 256 + c]       = f2bf(a1[nt][r]);
            Y[rr * 256 + 128 + c] = f2bf(a2[nt][r]);
        }
    }

    // coalesced copy-out: 4 lanes per node, 8 x 16B each
    const int m = lane >> 2, part = lane & 3;
    int gm = gn0 + m; if (gm >= N) gm = N - 1;
    #pragma unroll
    for (int j = 0; j < 8; ++j) {
        uint4 v = *(const uint4*)&Y[m * 256 + part * 64 + j * 8];
        *(uint4*)(Pb + (size_t)gm * 256 + part * 64 + j * 8) = v;
    }
}

// ---- single-tile epilogue: bias + LN + SiLU; result in acc, bf16 copy in LDS X ----
__device__ __forceinline__ void ln_silu_store1(
    f32x4* acc, const float* __restrict__ bias, const float* __restrict__ g,
    const float* __restrict__ be, unsigned short* X, int l15, int quad)
{
    float s[4] = {0,0,0,0}, q[4] = {0,0,0,0};
    #pragma unroll
    for (int nt = 0; nt < 8; ++nt) {
        float b = bias[nt * 16 + l15];
        #pragma unroll
        for (int r = 0; r < 4; ++r) {
            float x = acc[nt][r] + b; acc[nt][r] = x; s[r] += x; q[r] += x * x;
        }
    }
    #pragma unroll
    for (int r = 0; r < 4; ++r) { s[r] = red16(s[r]); q[r] = red16(q[r]); }
    #pragma unroll
    for (int r = 0; r < 4; ++r) {
        float mu = s[r] * 0.0078125f, v = q[r] * 0.0078125f - mu * mu;
        s[r] = mu; q[r] = fast_rsq(v + 1e-5f);
    }
    #pragma unroll
    for (int nt = 0; nt < 8; ++nt) {
        float gg = g[nt * 16 + l15], bb = be[nt * 16 + l15];
        #pragma unroll
        for (int r = 0; r < 4; ++r) {
            float a = q[r] * gg, c = bb - s[r] * a;
            float y = silu_f(fmaf(acc[nt][r], a, c));
            acc[nt][r] = y;
            X[(quad * 4 + r) * XSTR + nt * 16 + l15] = f2bf(y);
        }
    }
}

// -------------------- edge kernel: 1 wave, 16 edges (exact R4 + T5 setprio) ----
// R4 is the proven-best schedule (8 variants benched). Single added lever: wrap
// the MFMA clusters in s_setprio(1)/(0) — independent 1-wave blocks at different
// phases are exactly T5's favorable regime (attn +4-7%, m191).
__global__ __launch_bounds__(64, 4) void edge_kernel(
    const unsigned short* __restrict__ Pb, const int* __restrict__ ei,
    const float* __restrict__ coord, const float* __restrict__ eattr,
    const float* __restrict__ eW1,
    const float* __restrict__ eb1, const float* __restrict__ eg1, const float* __restrict__ ebe1,
    const unsigned short* __restrict__ eW2f,
    const float* __restrict__ eb2, const float* __restrict__ eg2, const float* __restrict__ ebe2,
    const unsigned short* __restrict__ cW1f,
    const float* __restrict__ cb1, const float* __restrict__ cg1, const float* __restrict__ cbe1,
    const float* __restrict__ cW2,
    unsigned short* __restrict__ aggb, float* __restrict__ coord_out, int E)
{
    __shared__ float S[16 * SSTR];                 // 8448 B; X aliases S
    unsigned short* X = (unsigned short*)S;

    const int lane = threadIdx.x;
    const int l15 = lane & 15, quad = lane >> 4;
    const int ge0 = blockIdx.x * 16;

    int el  = ge0 + l15;
    int elc = (el < E) ? el : (E - 1);
    int rowl = ei[elc], coll = ei[E + elc];
    float dx = coord[rowl * 3 + 0] - coord[coll * 3 + 0];
    float dy = coord[rowl * 3 + 1] - coord[coll * 3 + 1];
    float dz = coord[rowl * 3 + 2] - coord[coll * 3 + 2];
    float radial = dx * dx + dy * dy + dz * dz;
    float inv = fast_rcp(fast_sqrt(radial + 1e-8f) + 1.0f);
    float cdx = dx * inv, cdy = dy * inv, cdz = dz * inv;
    float ea = eattr[elc];

    // ---- stage P1[row] + P2[col] (bf16) summed to fp32 S[edge][128] ----
    {
        const int m = lane >> 2, part = lane & 3;
        int row_m = __shfl(rowl, m, 64);
        int col_m = __shfl(coll, m, 64);
        const unsigned short* p1 = Pb + (size_t)row_m * 256 + part * 32;
        const unsigned short* p2 = Pb + (size_t)col_m * 256 + 128 + part * 32;
        #pragma unroll
        for (int j = 0; j < 4; ++j) {
            uint4 a = *(const uint4*)(p1 + j * 8);
            uint4 b = *(const uint4*)(p2 + j * 8);
            float4 v0, v1;
            v0.x = bflo(a.x) + bflo(b.x); v0.y = bfhi(a.x) + bfhi(b.x);
            v0.z = bflo(a.y) + bflo(b.y); v0.w = bfhi(a.y) + bfhi(b.y);
            v1.x = bflo(a.z) + bflo(b.z); v1.y = bfhi(a.z) + bfhi(b.z);
            v1.z = bflo(a.w) + bflo(b.w); v1.w = bfhi(a.w) + bfhi(b.w);
            *(float4*)&S[m * SSTR + part * 32 + j * 8]     = v0;
            *(float4*)&S[m * SSTR + part * 32 + j * 8 + 4] = v1;
        }
    }

    // ---- acc init: C-layout read of S + rank-1 fp32 update (k=256,257) ----
    f32x4 acc[8];
    {
        float rad_r[4], ea_r[4];
        #pragma unroll
        for (int r = 0; r < 4; ++r) {
            rad_r[r] = __shfl(radial, quad * 4 + r, 64);
            ea_r[r]  = __shfl(ea,     quad * 4 + r, 64);
        }
        #pragma unroll
        for (int nt = 0; nt < 8; ++nt) {
            float w256 = eW1[256 * H + nt * 16 + l15];
            float w257 = eW1[257 * H + nt * 16 + l15];
            #pragma unroll
            for (int r = 0; r < 4; ++r) {
                float base = S[(quad * 4 + r) * SSTR + nt * 16 + l15];
                acc[nt][r] = base + rad_r[r] * w256 + ea_r[r] * w257;
            }
        }
    }

    // ---- epilogue 1 -> X (aliases S; all S reads precede these writes, in-wave order) ----
    ln_silu_store1(acc, eb1, eg1, ebe1, X, l15, quad);

    // ---- GEMM2: [16x128] @ eW2f ----
    f32x4 ac2[8];
    #pragma unroll
    for (int nt = 0; nt < 8; ++nt) ac2[nt] = (f32x4){0.f, 0.f, 0.f, 0.f};
    __builtin_amdgcn_s_setprio(1);
    for (int kb = 0; kb < 4; ++kb) {
        bf16x8 af = *(const bf16x8*)&X[l15 * XSTR + kb * 32 + quad * 8];
        const unsigned short* bp = eW2f + ((size_t)kb * 8) * 512 + (size_t)lane * 8;
        #pragma unroll
        for (int nt = 0; nt < 8; ++nt) {
            bf16x8 bf = *(const bf16x8*)(bp + (size_t)nt * 512);
            ac2[nt] = __builtin_amdgcn_mfma_f32_16x16x32_bf16(af, bf, ac2[nt], 0, 0, 0);
        }
    }
    __builtin_amdgcn_s_setprio(0);

    // ---- epilogue 2 = edge_feat -> X ----
    ln_silu_store1(ac2, eb2, eg2, ebe2, X, l15, quad);

    // ---- agg: packed-bf16 atomics, pairs read straight back from X (R11 pattern) ----
    {
        int rowm[4];
        #pragma unroll
        for (int r = 0; r < 4; ++r) rowm[r] = __shfl(rowl, quad * 4 + r, 64);
        #pragma unroll
        for (int c4 = 0; c4 < 4; ++c4) {
            #pragma unroll
            for (int r = 0; r < 4; ++r) {
                int geh = ge0 + quad * 4 + r;
                if (geh < E) {
                    unsigned int pkv =
                        *(const unsigned int*)&X[(quad * 4 + r) * XSTR + c4 * 32 + 2 * l15];
                    atomic_pk_add_bf16(aggb + (size_t)rowm[r] * H + c4 * 32 + 2 * l15, pkv);
                }
            }
        }
    }

    // ---- GEMM3: edge_feat @ cW1f ----
    f32x4 acc3[8];
    #pragma unroll
    for (int nt = 0; nt < 8; ++nt) acc3[nt] = (f32x4){0.f, 0.f, 0.f, 0.f};
    __builtin_amdgcn_s_setprio(1);
    for (int kb = 0; kb < 4; ++kb) {
        bf16x8 af = *(const bf16x8*)&X[l15 * XSTR + kb * 32 + quad * 8];
        const unsigned short* bp = cW1f + ((size_t)kb * 8) * 512 + (size_t)lane * 8;
        #pragma unroll
        for (int nt = 0; nt < 8; ++nt) {
            bf16x8 bf = *(const bf16x8*)(bp + (size_t)nt * 512);
            acc3[nt] = __builtin_amdgcn_mfma_f32_16x16x32_bf16(af, bf, acc3[nt], 0, 0, 0);
        }
    }
    __builtin_amdgcn_s_setprio(0);

    // ---- epilogue 3: bias + LN + SiLU, dot cW2 -> cm; coord atomics ----
    {
        float s[4] = {0,0,0,0}, q[4] = {0,0,0,0};
        #pragma unroll
        for (int nt = 0; nt < 8; ++nt) {
            float b = cb1[nt * 16 + l15];
            #pragma unroll
            for (int r = 0; r < 4; ++r) {
                float x = acc3[nt][r] + b; acc3[nt][r] = x; s[r] += x; q[r] += x * x;
            }
        }
        #pragma unroll
        for (int r = 0; r < 4; ++r) { s[r] = red16(s[r]); q[r] = red16(q[r]); }
        #pragma unroll
        for (int r = 0; r < 4; ++r) {
            float mu = s[r] * 0.0078125f, v = q[r] * 0.0078125f - mu * mu;
            s[r] = mu; q[r] = fast_rsq(v + 1e-5f);
        }
        float cm[4] = {0,0,0,0};
        #pragma unroll
        for (int nt = 0; nt < 8; ++nt) {
            float gg = cg1[nt * 16 + l15], bb = cbe1[nt * 16 + l15];
            float w2 = cW2[nt * 16 + l15];
            #pragma unroll
            for (int r = 0; r < 4; ++r) {
                float a = q[r] * gg, c = bb - s[r] * a;
                cm[r] += silu_f(fmaf(acc3[nt][r], a, c)) * w2;
            }
        }
        #pragma unroll
        for (int r = 0; r < 4; ++r) cm[r] = red16(cm[r]);
        #pragma unroll
        for (int r = 0; r < 4; ++r) {
            int src = quad * 4 + r;
            float cdxr = __shfl(cdx, src, 64);
            float cdyr = __shfl(cdy, src, 64);
            float cdzr = __shfl(cdz, src, 64);
            int rw = __shfl(rowl, src, 64);
            float comp = (l15 == 0) ? cdxr : ((l15 == 1) ? cdyr : cdzr);
            int geh = ge0 + src;
            if (l15 < 3 && geh < E)
                atomicAdd(&coord_out[(size_t)rw * 3 + l15], comp * cm[r]);
        }
    }
}

// ---- node kernel: 256 threads = 4 independent waves, 16 nodes each ----
__global__ __launch_bounds__(256, 4) void node_kernel(
    const unsigned short* __restrict__ hb, const float* __restrict__ h,
    const unsigned short* __restrict__ aggb,
    const unsigned short* __restrict__ nW1f,
    const float* __restrict__ nb1, const float* __restrict__ ng1, const float* __restrict__ nbe1,
    const unsigned short* __restrict__ nW2f, const float* __restrict__ nb2,
    float* __restrict__ out, int N)
{
    __shared__ unsigned short Xs[4][16 * XSTR];

    const int wv   = threadIdx.x >> 6;
    const int lane = threadIdx.x & 63;
    const int l15 = lane & 15, quad = lane >> 4;
    const int gn0 = (blockIdx.x * 4 + wv) * 16;
    unsigned short* X = &Xs[wv][0];

    if (gn0 >= N) return;
    int nl = gn0 + l15; if (nl >= N) nl = N - 1;

    f32x4 acc[8];
    #pragma unroll
    for (int nt = 0; nt < 8; ++nt) acc[nt] = (f32x4){0.f, 0.f, 0.f, 0.f};

    for (int kb = 0; kb < 8; ++kb) {
        int ko = (kb & 3) * 32 + quad * 8;
        const unsigned short* src = (kb < 4) ? hb : aggb;
        bf16x8 af = *(const bf16x8*)(src + (size_t)nl * H + ko);
        const unsigned short* bp = nW1f + ((size_t)kb * 8) * 512 + (size_t)lane * 8;
        #pragma unroll
        for (int nt = 0; nt < 8; ++nt) {
            bf16x8 bf = *(const bf16x8*)(bp + (size_t)nt * 512);
            acc[nt] = __builtin_amdgcn_mfma_f32_16x16x32_bf16(af, bf, acc[nt], 0, 0, 0);
        }
    }

    ln_silu_store1(acc, nb1, ng1, nbe1, X, l15, quad);

    f32x4 ac2[8];
    #pragma unroll
    for (int nt = 0; nt < 8; ++nt) ac2[nt] = (f32x4){0.f, 0.f, 0.f, 0.f};
    for (int kb = 0; kb < 4; ++kb) {
        bf16x8 af = *(const bf16x8*)&X[l15 * XSTR + kb * 32 + quad * 8];
        const unsigned short* bp = nW2f + ((size_t)kb * 8) * 512 + (size_t)lane * 8;
        #pragma unroll
        for (int nt = 0; nt < 8; ++nt) {
            bf16x8 bf = *(const bf16x8*)(bp + (size_t)nt * 512);
            ac2[nt] = __builtin_amdgcn_mfma_f32_16x16x32_bf16(af, bf, ac2[nt], 0, 0, 0);
        }
    }

    #pragma unroll
    for (int nt = 0; nt < 8; ++nt) {
        float b = nb2[nt * 16 + l15];
        #pragma unroll
        for (int r = 0; r < 4; ++r) {
            int gn = gn0 + quad * 4 + r;
            if (gn < N) {
                size_t idx = (size_t)gn * H + nt * 16 + l15;
                out[idx] = ac2[nt][r] + b + h[idx];
            }
        }
    }
}

// -------------------- launch --------------------
extern "C" void kernel_launch(void* const* d_in, const int* in_sizes, int n_in,
                              void* d_out, int out_size, void* d_ws, size_t ws_size,
                              hipStream_t stream) {
    const float* h     = (const float*)d_in[0];
    const int*   ei    = (const int*)d_in[1];
    const float* coord = (const float*)d_in[2];
    const float* eattr = (const float*)d_in[3];
    const float* eW1   = (const float*)d_in[4];
    const float* eb1   = (const float*)d_in[5];
    const float* eg1   = (const float*)d_in[6];
    const float* ebe1  = (const float*)d_in[7];
    const float* eW2   = (const float*)d_in[8];
    const float* eb2   = (const float*)d_in[9];
    const float* eg2   = (const float*)d_in[10];
    const float* ebe2  = (const float*)d_in[11];
    const float* nW1   = (const float*)d_in[12];
    const float* nb1   = (const float*)d_in[13];
    const float* ng1   = (const float*)d_in[14];
    const float* nbe1  = (const float*)d_in[15];
    const float* nW2   = (const float*)d_in[16];
    const float* nb2   = (const float*)d_in[17];
    const float* cW1   = (const float*)d_in[18];
    const float* cb1   = (const float*)d_in[19];
    const float* cg1   = (const float*)d_in[20];
    const float* cbe1  = (const float*)d_in[21];
    const float* cW2   = (const float*)d_in[22];

    const int N = in_sizes[0] / H;
    const int E = in_sizes[1] / 2;

    float* out       = (float*)d_out;
    float* coord_out = out + (size_t)N * H;

    // ---- workspace layout ----
    char* ws = (char*)d_ws;
    size_t o = 0;
    unsigned short* aggb = (unsigned short*)(ws + o); o += (size_t)N * H * 2;
    unsigned short* hb   = (unsigned short*)(ws + o); o += (size_t)N * H * 2;
    unsigned short* Pb   = (unsigned short*)(ws + o); o += (size_t)N * 256 * 2;
    unsigned short* eW1f = (unsigned short*)(ws + o); o += (size_t)H * KE * 2;
    unsigned short* eW2f = (unsigned short*)(ws + o); o += (size_t)H * H * 2;
    unsigned short* cW1f = (unsigned short*)(ws + o); o += (size_t)H * H * 2;
    unsigned short* nW1f = (unsigned short*)(ws + o); o += (size_t)H * KN * 2;
    unsigned short* nW2f = (unsigned short*)(ws + o); o += (size_t)H * H * 2;

    // ---- fused prep: hb | aggb zero | coord copy | weight frags ----
    const int n4_h   = N * H / 4;
    const int n4_agg = N * H / 8;          // 16B groups over N*H*2 bytes
    const int n_co   = N * 3;
    const int b0 = (n4_h   + 255) / 256;
    const int b1 = b0 + (n4_agg + 255) / 256;
    const int b2 = b1 + (n_co   + 255) / 256;
    const int bw = (4096 + 4096 + 2048 + 2048 + 2048 + 255) / 256;  // 56
    prep_all<<<b2 + bw, 256, 0, stream>>>(
        h, hb, n4_h, (float*)aggb, n4_agg, coord, coord_out, n_co,
        eW1, eW2, cW1, nW1, nW2,
        eW1f, eW2f, cW1f, nW1f, nW2f, b0, b1, b2);

    proj_kernel<<<(N + 63) / 64, 256, 0, stream>>>(hb, eW1f, Pb, N);

    edge_kernel<<<(E + 15) / 16, 64, 0, stream>>>(
        Pb, ei, coord, eattr,
        eW1, eb1, eg1, ebe1,
        eW2f, eb2, eg2, ebe2,
        cW1f, cb1, cg1, cbe1, cW2,
        aggb, coord_out, E);

    node_kernel<<<(N + 63) / 64, 256, 0, stream>>>(
        hb, h, aggb, nW1f, nb1, ng1, nbe1, nW2f, nb2, out, N);
}

// Round 11
// 291.716 us; speedup vs baseline: 1.1365x; 1.0031x over previous
//
#include <hip/hip_runtime.h>
#include <math.h>

#define H 128
#define KE 256      // eW1 MFMA K (k=256,257 via fp32 rank-1 update)
#define KN 256      // node GEMM1 K (2H)
#define XSTR 136    // LDS X row stride (bf16 elems)
#define SSTR 132    // LDS S row stride (fp32 elems) — breaks 4-way bank alias

typedef __attribute__((ext_vector_type(8))) short bf16x8;
typedef __attribute__((ext_vector_type(4))) float f32x4;

__device__ __forceinline__ float fast_rcp(float x) {
#if defined(__has_builtin) && __has_builtin(__builtin_amdgcn_rcpf)
    return __builtin_amdgcn_rcpf(x);
#else
    return 1.0f / x;
#endif
}
__device__ __forceinline__ float fast_rsq(float x) {
#if defined(__has_builtin) && __has_builtin(__builtin_amdgcn_rsqf)
    return __builtin_amdgcn_rsqf(x);
#else
    return rsqrtf(x);
#endif
}
__device__ __forceinline__ float fast_sqrt(float x) {
#if defined(__has_builtin) && __has_builtin(__builtin_amdgcn_sqrtf)
    return __builtin_amdgcn_sqrtf(x);
#else
    return sqrtf(x);
#endif
}

// silu via v_rcp_f32 (1 ulp) instead of IEEE divide expansion (~10-14 VALU ops)
__device__ __forceinline__ float silu_f(float x) {
    return x * fast_rcp(1.0f + __expf(-x));
}

__device__ __forceinline__ unsigned short f2bf(float f) {
    unsigned int u = __float_as_uint(f);
    unsigned int r = u + 0x7FFFu + ((u >> 16) & 1u);
    return (unsigned short)(r >> 16);
}

__device__ __forceinline__ unsigned int pkbf(float a, float b) {
#if defined(__has_builtin)
#if __has_builtin(__builtin_amdgcn_cvt_pk_bf16_f32)
    typedef __attribute__((ext_vector_type(2))) __bf16 bf16x2_t;
    bf16x2_t v = __builtin_amdgcn_cvt_pk_bf16_f32(a, b);
    return *(unsigned int*)&v;
#else
    return (unsigned int)f2bf(a) | ((unsigned int)f2bf(b) << 16);
#endif
#else
    return (unsigned int)f2bf(a) | ((unsigned int)f2bf(b) << 16);
#endif
}

__device__ __forceinline__ float bflo(unsigned int w) { return __uint_as_float(w << 16); }
__device__ __forceinline__ float bfhi(unsigned int w) { return __uint_as_float(w & 0xFFFF0000u); }

// hardware packed-bf16 atomic add (gfx90a+/gfx950), fire-and-forget
__device__ __forceinline__ void atomic_pk_add_bf16(unsigned short* addr, unsigned int pkv) {
    asm volatile("global_atomic_pk_add_bf16 %0, %1, off"
                 :: "v"(addr), "v"(pkv) : "memory");
}

// ---- 16-lane sum reduction via DPP row rotations ----
template<int CTRL>
__device__ __forceinline__ float dpp_add(float x) {
    int t = __builtin_amdgcn_update_dpp(0, __float_as_int(x), CTRL, 0xF, 0xF, true);
    return x + __int_as_float(t);
}
__device__ __forceinline__ float red16(float x) {
    x = dpp_add<0x128>(x);
    x = dpp_add<0x124>(x);
    x = dpp_add<0x122>(x);
    x = dpp_add<0x121>(x);
    return x;
}

// ---- one weight fragment: W[K][128] fp32 -> fragment-linear Wf[f][8] bf16 ----
__device__ __forceinline__ void wfrag(const float* __restrict__ W,
                                      unsigned short* __restrict__ Wf, int f) {
    int kb = f >> 9, rem = f & 511;
    int nt = rem >> 6, lane = rem & 63;
    int quad = lane >> 4, l15 = lane & 15;
    int n = nt * 16 + l15, k0 = kb * 32 + quad * 8;
    union { bf16x8 v; unsigned short u[8]; } pk;
    #pragma unroll
    for (int j = 0; j < 8; ++j) pk.u[j] = f2bf(W[(size_t)(k0 + j) * H + n]);
    *(bf16x8*)&Wf[(size_t)f * 8] = pk.v;
}

// ---- fused prep: hb convert | aggb zero | coord copy | 5 weight transposes ----
__global__ __launch_bounds__(256) void prep_all(
    const float* __restrict__ h, unsigned short* __restrict__ hb, int n4_h,
    float* __restrict__ aggz, int n4_agg,
    const float* __restrict__ coord, float* __restrict__ coord_out, int n_coord,
    const float* __restrict__ eW1, const float* __restrict__ eW2,
    const float* __restrict__ cW1, const float* __restrict__ nW1,
    const float* __restrict__ nW2,
    unsigned short* __restrict__ eW1f, unsigned short* __restrict__ eW2f,
    unsigned short* __restrict__ cW1f, unsigned short* __restrict__ nW1f,
    unsigned short* __restrict__ nW2f,
    int b0, int b1, int b2)
{
    int b = blockIdx.x;
    int t = threadIdx.x;
    if (b < b0) {
        int i = b * 256 + t;
        if (i < n4_h) {
            float4 f = ((const float4*)h)[i];
            ((uint2*)hb)[i] = make_uint2(pkbf(f.x, f.y), pkbf(f.z, f.w));
        }
    } else if (b < b1) {
        int i = (b - b0) * 256 + t;
        if (i < n4_agg) ((float4*)aggz)[i] = (float4){0.f, 0.f, 0.f, 0.f};
    } else if (b < b2) {
        int i = (b - b1) * 256 + t;
        if (i < n_coord) coord_out[i] = coord[i];
    } else {
        int idx = (b - b2) * 256 + t;
        if      (idx <  4096) wfrag(eW1, eW1f, idx);
        else if (idx <  8192) wfrag(nW1, nW1f, idx - 4096);
        else if (idx < 10240) wfrag(eW2, eW2f, idx - 8192);
        else if (idx < 12288) wfrag(cW1, cW1f, idx - 10240);
        else if (idx < 14336) wfrag(nW2, nW2f, idx - 12288);
    }
}

// ---- proj kernel: Pb[n][0:128] = h[n]@eW1[0:128,:], Pb[n][128:256] = h[n]@eW1[128:256,:]
__global__ __launch_bounds__(256, 4) void proj_kernel(
    const unsigned short* __restrict__ hb,
    const unsigned short* __restrict__ eW1f,
    unsigned short* __restrict__ Pb, int N)
{
    __shared__ unsigned short Ys[4][16 * 256];   // 8 KB per wave

    const int wv = threadIdx.x >> 6;
    const int lane = threadIdx.x & 63;
    const int l15 = lane & 15, quad = lane >> 4;
    const int gn0 = (blockIdx.x * 4 + wv) * 16;
    unsigned short* Y = &Ys[wv][0];

    if (gn0 >= N) return;
    int nl = gn0 + l15; if (nl >= N) nl = N - 1;

    f32x4 a1[8], a2[8];
    #pragma unroll
    for (int nt = 0; nt < 8; ++nt) {
        a1[nt] = (f32x4){0.f, 0.f, 0.f, 0.f};
        a2[nt] = (f32x4){0.f, 0.f, 0.f, 0.f};
    }

    __builtin_amdgcn_s_setprio(1);
    for (int kb = 0; kb < 4; ++kb) {
        int ko = kb * 32 + quad * 8;
        bf16x8 af = *(const bf16x8*)(hb + (size_t)nl * H + ko);
        const unsigned short* bp1 = eW1f + ((size_t)kb * 8) * 512 + (size_t)lane * 8;
        const unsigned short* bp2 = eW1f + ((size_t)(kb + 4) * 8) * 512 + (size_t)lane * 8;
        #pragma unroll
        for (int nt = 0; nt < 8; ++nt) {
            bf16x8 b1 = *(const bf16x8*)(bp1 + (size_t)nt * 512);
            bf16x8 b2 = *(const bf16x8*)(bp2 + (size_t)nt * 512);
            a1[nt] = __builtin_amdgcn_mfma_f32_16x16x32_bf16(af, b1, a1[nt], 0, 0, 0);
            a2[nt] = __builtin_amdgcn_mfma_f32_16x16x32_bf16(af, b2, a2[nt], 0, 0, 0);
        }
    }
    __builtin_amdgcn_s_setprio(0);

    // C-layout -> LDS bf16 rows [node][256]
    #pragma unroll
    for (int nt = 0; nt < 8; ++nt) {
        int c = nt * 16 + l15;
        #pragma unroll
        for (int r = 0; r < 4; ++r) {
            int rr = quad * 4 + r;
            Y[rr * 256 + c]       = f2bf(a1[nt][r]);
            Y[rr * 256 + 128 + c] = f2bf(a2[nt][r]);
        }
    }

    // coalesced copy-out: 4 lanes per node, 8 x 16B each
    const int m = lane >> 2, part = lane & 3;
    int gm = gn0 + m; if (gm >= N) gm = N - 1;
    #pragma unroll
    for (int j = 0; j < 8; ++j) {
        uint4 v = *(const uint4*)&Y[m * 256 + part * 64 + j * 8];
        *(uint4*)(Pb + (size_t)gm * 256 + part * 64 + j * 8) = v;
    }
}

// ---- single-tile epilogue: bias + LN + SiLU; result in acc, bf16 copy in LDS X ----
__device__ __forceinline__ void ln_silu_store1(
    f32x4* acc, const float* __restrict__ bias, const float* __restrict__ g,
    const float* __restrict__ be, unsigned short* X, int l15, int quad)
{
    float s[4] = {0,0,0,0}, q[4] = {0,0,0,0};
    #pragma unroll
    for (int nt = 0; nt < 8; ++nt) {
        float b = bias[nt * 16 + l15];
        #pragma unroll
        for (int r = 0; r < 4; ++r) {
            float x = acc[nt][r] + b; acc[nt][r] = x; s[r] += x; q[r] += x * x;
        }
    }
    #pragma unroll
    for (int r = 0; r < 4; ++r) { s[r] = red16(s[r]); q[r] = red16(q[r]); }
    #pragma unroll
    for (int r = 0; r < 4; ++r) {
        float mu = s[r] * 0.0078125f, v = q[r] * 0.0078125f - mu * mu;
        s[r] = mu; q[r] = fast_rsq(v + 1e-5f);
    }
    #pragma unroll
    for (int nt = 0; nt < 8; ++nt) {
        float gg = g[nt * 16 + l15], bb = be[nt * 16 + l15];
        #pragma unroll
        for (int r = 0; r < 4; ++r) {
            float a = q[r] * gg, c = bb - s[r] * a;
            float y = silu_f(fmaf(acc[nt][r], a, c));
            acc[nt][r] = y;
            X[(quad * 4 + r) * XSTR + nt * 16 + l15] = f2bf(y);
        }
    }
}

// -------------------- edge kernel: 1 wave, 16 edges (exact R4 + T5 setprio) ----
// Champion schedule (8 variants benched); setprio verified +4.4% in R10.
__global__ __launch_bounds__(64, 4) void edge_kernel(
    const unsigned short* __restrict__ Pb, const int* __restrict__ ei,
    const float* __restrict__ coord, const float* __restrict__ eattr,
    const float* __restrict__ eW1,
    const float* __restrict__ eb1, const float* __restrict__ eg1, const float* __restrict__ ebe1,
    const unsigned short* __restrict__ eW2f,
    const float* __restrict__ eb2, const float* __restrict__ eg2, const float* __restrict__ ebe2,
    const unsigned short* __restrict__ cW1f,
    const float* __restrict__ cb1, const float* __restrict__ cg1, const float* __restrict__ cbe1,
    const float* __restrict__ cW2,
    unsigned short* __restrict__ aggb, float* __restrict__ coord_out, int E)
{
    __shared__ float S[16 * SSTR];                 // 8448 B; X aliases S
    unsigned short* X = (unsigned short*)S;

    const int lane = threadIdx.x;
    const int l15 = lane & 15, quad = lane >> 4;
    const int ge0 = blockIdx.x * 16;

    int el  = ge0 + l15;
    int elc = (el < E) ? el : (E - 1);
    int rowl = ei[elc], coll = ei[E + elc];
    float dx = coord[rowl * 3 + 0] - coord[coll * 3 + 0];
    float dy = coord[rowl * 3 + 1] - coord[coll * 3 + 1];
    float dz = coord[rowl * 3 + 2] - coord[coll * 3 + 2];
    float radial = dx * dx + dy * dy + dz * dz;
    float inv = fast_rcp(fast_sqrt(radial + 1e-8f) + 1.0f);
    float cdx = dx * inv, cdy = dy * inv, cdz = dz * inv;
    float ea = eattr[elc];

    // ---- stage P1[row] + P2[col] (bf16) summed to fp32 S[edge][128] ----
    {
        const int m = lane >> 2, part = lane & 3;
        int row_m = __shfl(rowl, m, 64);
        int col_m = __shfl(coll, m, 64);
        const unsigned short* p1 = Pb + (size_t)row_m * 256 + part * 32;
        const unsigned short* p2 = Pb + (size_t)col_m * 256 + 128 + part * 32;
        #pragma unroll
        for (int j = 0; j < 4; ++j) {
            uint4 a = *(const uint4*)(p1 + j * 8);
            uint4 b = *(const uint4*)(p2 + j * 8);
            float4 v0, v1;
            v0.x = bflo(a.x) + bflo(b.x); v0.y = bfhi(a.x) + bfhi(b.x);
            v0.z = bflo(a.y) + bflo(b.y); v0.w = bfhi(a.y) + bfhi(b.y);
            v1.x = bflo(a.z) + bflo(b.z); v1.y = bfhi(a.z) + bfhi(b.z);
            v1.z = bflo(a.w) + bflo(b.w); v1.w = bfhi(a.w) + bfhi(b.w);
            *(float4*)&S[m * SSTR + part * 32 + j * 8]     = v0;
            *(float4*)&S[m * SSTR + part * 32 + j * 8 + 4] = v1;
        }
    }

    // ---- acc init: C-layout read of S + rank-1 fp32 update (k=256,257) ----
    f32x4 acc[8];
    {
        float rad_r[4], ea_r[4];
        #pragma unroll
        for (int r = 0; r < 4; ++r) {
            rad_r[r] = __shfl(radial, quad * 4 + r, 64);
            ea_r[r]  = __shfl(ea,     quad * 4 + r, 64);
        }
        #pragma unroll
        for (int nt = 0; nt < 8; ++nt) {
            float w256 = eW1[256 * H + nt * 16 + l15];
            float w257 = eW1[257 * H + nt * 16 + l15];
            #pragma unroll
            for (int r = 0; r < 4; ++r) {
                float base = S[(quad * 4 + r) * SSTR + nt * 16 + l15];
                acc[nt][r] = base + rad_r[r] * w256 + ea_r[r] * w257;
            }
        }
    }

    // ---- epilogue 1 -> X (aliases S; all S reads precede these writes, in-wave order) ----
    ln_silu_store1(acc, eb1, eg1, ebe1, X, l15, quad);

    // ---- GEMM2: [16x128] @ eW2f ----
    f32x4 ac2[8];
    #pragma unroll
    for (int nt = 0; nt < 8; ++nt) ac2[nt] = (f32x4){0.f, 0.f, 0.f, 0.f};
    __builtin_amdgcn_s_setprio(1);
    for (int kb = 0; kb < 4; ++kb) {
        bf16x8 af = *(const bf16x8*)&X[l15 * XSTR + kb * 32 + quad * 8];
        const unsigned short* bp = eW2f + ((size_t)kb * 8) * 512 + (size_t)lane * 8;
        #pragma unroll
        for (int nt = 0; nt < 8; ++nt) {
            bf16x8 bf = *(const bf16x8*)(bp + (size_t)nt * 512);
            ac2[nt] = __builtin_amdgcn_mfma_f32_16x16x32_bf16(af, bf, ac2[nt], 0, 0, 0);
        }
    }
    __builtin_amdgcn_s_setprio(0);

    // ---- epilogue 2 = edge_feat -> X ----
    ln_silu_store1(ac2, eb2, eg2, ebe2, X, l15, quad);

    // ---- agg: packed-bf16 atomics, pairs read straight back from X (R11 pattern) ----
    {
        int rowm[4];
        #pragma unroll
        for (int r = 0; r < 4; ++r) rowm[r] = __shfl(rowl, quad * 4 + r, 64);
        #pragma unroll
        for (int c4 = 0; c4 < 4; ++c4) {
            #pragma unroll
            for (int r = 0; r < 4; ++r) {
                int geh = ge0 + quad * 4 + r;
                if (geh < E) {
                    unsigned int pkv =
                        *(const unsigned int*)&X[(quad * 4 + r) * XSTR + c4 * 32 + 2 * l15];
                    atomic_pk_add_bf16(aggb + (size_t)rowm[r] * H + c4 * 32 + 2 * l15, pkv);
                }
            }
        }
    }

    // ---- GEMM3: edge_feat @ cW1f ----
    f32x4 acc3[8];
    #pragma unroll
    for (int nt = 0; nt < 8; ++nt) acc3[nt] = (f32x4){0.f, 0.f, 0.f, 0.f};
    __builtin_amdgcn_s_setprio(1);
    for (int kb = 0; kb < 4; ++kb) {
        bf16x8 af = *(const bf16x8*)&X[l15 * XSTR + kb * 32 + quad * 8];
        const unsigned short* bp = cW1f + ((size_t)kb * 8) * 512 + (size_t)lane * 8;
        #pragma unroll
        for (int nt = 0; nt < 8; ++nt) {
            bf16x8 bf = *(const bf16x8*)(bp + (size_t)nt * 512);
            acc3[nt] = __builtin_amdgcn_mfma_f32_16x16x32_bf16(af, bf, acc3[nt], 0, 0, 0);
        }
    }
    __builtin_amdgcn_s_setprio(0);

    // ---- epilogue 3: bias + LN + SiLU, dot cW2 -> cm; coord atomics ----
    {
        float s[4] = {0,0,0,0}, q[4] = {0,0,0,0};
        #pragma unroll
        for (int nt = 0; nt < 8; ++nt) {
            float b = cb1[nt * 16 + l15];
            #pragma unroll
            for (int r = 0; r < 4; ++r) {
                float x = acc3[nt][r] + b; acc3[nt][r] = x; s[r] += x; q[r] += x * x;
            }
        }
        #pragma unroll
        for (int r = 0; r < 4; ++r) { s[r] = red16(s[r]); q[r] = red16(q[r]); }
        #pragma unroll
        for (int r = 0; r < 4; ++r) {
            float mu = s[r] * 0.0078125f, v = q[r] * 0.0078125f - mu * mu;
            s[r] = mu; q[r] = fast_rsq(v + 1e-5f);
        }
        float cm[4] = {0,0,0,0};
        #pragma unroll
        for (int nt = 0; nt < 8; ++nt) {
            float gg = cg1[nt * 16 + l15], bb = cbe1[nt * 16 + l15];
            float w2 = cW2[nt * 16 + l15];
            #pragma unroll
            for (int r = 0; r < 4; ++r) {
                float a = q[r] * gg, c = bb - s[r] * a;
                cm[r] += silu_f(fmaf(acc3[nt][r], a, c)) * w2;
            }
        }
        #pragma unroll
        for (int r = 0; r < 4; ++r) cm[r] = red16(cm[r]);
        #pragma unroll
        for (int r = 0; r < 4; ++r) {
            int src = quad * 4 + r;
            float cdxr = __shfl(cdx, src, 64);
            float cdyr = __shfl(cdy, src, 64);
            float cdzr = __shfl(cdz, src, 64);
            int rw = __shfl(rowl, src, 64);
            float comp = (l15 == 0) ? cdxr : ((l15 == 1) ? cdyr : cdzr);
            int geh = ge0 + src;
            if (l15 < 3 && geh < E)
                atomicAdd(&coord_out[(size_t)rw * 3 + l15], comp * cm[r]);
        }
    }
}

// ---- node kernel: 256 threads = 4 independent waves, 16 nodes each ----
__global__ __launch_bounds__(256, 4) void node_kernel(
    const unsigned short* __restrict__ hb, const float* __restrict__ h,
    const unsigned short* __restrict__ aggb,
    const unsigned short* __restrict__ nW1f,
    const float* __restrict__ nb1, const float* __restrict__ ng1, const float* __restrict__ nbe1,
    const unsigned short* __restrict__ nW2f, const float* __restrict__ nb2,
    float* __restrict__ out, int N)
{
    __shared__ unsigned short Xs[4][16 * XSTR];

    const int wv   = threadIdx.x >> 6;
    const int lane = threadIdx.x & 63;
    const int l15 = lane & 15, quad = lane >> 4;
    const int gn0 = (blockIdx.x * 4 + wv) * 16;
    unsigned short* X = &Xs[wv][0];

    if (gn0 >= N) return;
    int nl = gn0 + l15; if (nl >= N) nl = N - 1;

    f32x4 acc[8];
    #pragma unroll
    for (int nt = 0; nt < 8; ++nt) acc[nt] = (f32x4){0.f, 0.f, 0.f, 0.f};

    __builtin_amdgcn_s_setprio(1);
    for (int kb = 0; kb < 8; ++kb) {
        int ko = (kb & 3) * 32 + quad * 8;
        const unsigned short* src = (kb < 4) ? hb : aggb;
        bf16x8 af = *(const bf16x8*)(src + (size_t)nl * H + ko);
        const unsigned short* bp = nW1f + ((size_t)kb * 8) * 512 + (size_t)lane * 8;
        #pragma unroll
        for (int nt = 0; nt < 8; ++nt) {
            bf16x8 bf = *(const bf16x8*)(bp + (size_t)nt * 512);
            acc[nt] = __builtin_amdgcn_mfma_f32_16x16x32_bf16(af, bf, acc[nt], 0, 0, 0);
        }
    }
    __builtin_amdgcn_s_setprio(0);

    ln_silu_store1(acc, nb1, ng1, nbe1, X, l15, quad);

    f32x4 ac2[8];
    #pragma unroll
    for (int nt = 0; nt < 8; ++nt) ac2[nt] = (f32x4){0.f, 0.f, 0.f, 0.f};
    __builtin_amdgcn_s_setprio(1);
    for (int kb = 0; kb < 4; ++kb) {
        bf16x8 af = *(const bf16x8*)&X[l15 * XSTR + kb * 32 + quad * 8];
        const unsigned short* bp = nW2f + ((size_t)kb * 8) * 512 + (size_t)lane * 8;
        #pragma unroll
        for (int nt = 0; nt < 8; ++nt) {
            bf16x8 bf = *(const bf16x8*)(bp + (size_t)nt * 512);
            ac2[nt] = __builtin_amdgcn_mfma_f32_16x16x32_bf16(af, bf, ac2[nt], 0, 0, 0);
        }
    }
    __builtin_amdgcn_s_setprio(0);

    #pragma unroll
    for (int nt = 0; nt < 8; ++nt) {
        float b = nb2[nt * 16 + l15];
        #pragma unroll
        for (int r = 0; r < 4; ++r) {
            int gn = gn0 + quad * 4 + r;
            if (gn < N) {
                size_t idx = (size_t)gn * H + nt * 16 + l15;
                out[idx] = ac2[nt][r] + b + h[idx];
            }
        }
    }
}

// -------------------- launch --------------------
extern "C" void kernel_launch(void* const* d_in, const int* in_sizes, int n_in,
                              void* d_out, int out_size, void* d_ws, size_t ws_size,
                              hipStream_t stream) {
    const float* h     = (const float*)d_in[0];
    const int*   ei    = (const int*)d_in[1];
    const float* coord = (const float*)d_in[2];
    const float* eattr = (const float*)d_in[3];
    const float* eW1   = (const float*)d_in[4];
    const float* eb1   = (const float*)d_in[5];
    const float* eg1   = (const float*)d_in[6];
    const float* ebe1  = (const float*)d_in[7];
    const float* eW2   = (const float*)d_in[8];
    const float* eb2   = (const float*)d_in[9];
    const float* eg2   = (const float*)d_in[10];
    const float* ebe2  = (const float*)d_in[11];
    const float* nW1   = (const float*)d_in[12];
    const float* nb1   = (const float*)d_in[13];
    const float* ng1   = (const float*)d_in[14];
    const float* nbe1  = (const float*)d_in[15];
    const float* nW2   = (const float*)d_in[16];
    const float* nb2   = (const float*)d_in[17];
    const float* cW1   = (const float*)d_in[18];
    const float* cb1   = (const float*)d_in[19];
    const float* cg1   = (const float*)d_in[20];
    const float* cbe1  = (const float*)d_in[21];
    const float* cW2   = (const float*)d_in[22];

    const int N = in_sizes[0] / H;
    const int E = in_sizes[1] / 2;

    float* out       = (float*)d_out;
    float* coord_out = out + (size_t)N * H;

    // ---- workspace layout ----
    char* ws = (char*)d_ws;
    size_t o = 0;
    unsigned short* aggb = (unsigned short*)(ws + o); o += (size_t)N * H * 2;
    unsigned short* hb   = (unsigned short*)(ws + o); o += (size_t)N * H * 2;
    unsigned short* Pb   = (unsigned short*)(ws + o); o += (size_t)N * 256 * 2;
    unsigned short* eW1f = (unsigned short*)(ws + o); o += (size_t)H * KE * 2;
    unsigned short* eW2f = (unsigned short*)(ws + o); o += (size_t)H * H * 2;
    unsigned short* cW1f = (unsigned short*)(ws + o); o += (size_t)H * H * 2;
    unsigned short* nW1f = (unsigned short*)(ws + o); o += (size_t)H * KN * 2;
    unsigned short* nW2f = (unsigned short*)(ws + o); o += (size_t)H * H * 2;

    // ---- fused prep: hb | aggb zero | coord copy | weight frags ----
    const int n4_h   = N * H / 4;
    const int n4_agg = N * H / 8;          // 16B groups over N*H*2 bytes
    const int n_co   = N * 3;
    const int b0 = (n4_h   + 255) / 256;
    const int b1 = b0 + (n4_agg + 255) / 256;
    const int b2 = b1 + (n_co   + 255) / 256;
    const int bw = (4096 + 4096 + 2048 + 2048 + 2048 + 255) / 256;  // 56
    prep_all<<<b2 + bw, 256, 0, stream>>>(
        h, hb, n4_h, (float*)aggb, n4_agg, coord, coord_out, n_co,
        eW1, eW2, cW1, nW1, nW2,
        eW1f, eW2f, cW1f, nW1f, nW2f, b0, b1, b2);

    proj_kernel<<<(N + 63) / 64, 256, 0, stream>>>(hb, eW1f, Pb, N);

    edge_kernel<<<(E + 15) / 16, 64, 0, stream>>>(
        Pb, ei, coord, eattr,
        eW1, eb1, eg1, ebe1,
        eW2f, eb2, eg2, ebe2,
        cW1f, cb1, cg1, cbe1, cW2,
        aggb, coord_out, E);

    node_kernel<<<(N + 63) / 64, 256, 0, stream>>>(
        hb, h, aggb, nW1f, nb1, ng1, nbe1, nW2f, nb2, out, N);
}